// Round 6
// baseline (59410.052 us; speedup 1.0000x reference)
//
#include <hip/hip_runtime.h>
#include <math.h>

// SimpleNeuroSAT on MI355X — round 5: lane-major CSR gather (64 chains/wave,
// 16B chunks), LDS-staged cl lists, stats finalize fused into last block.
// Structure relied on: clause c owns cells 3c..3c+2, graphs contiguous, n_vars=100000.
// MFMA 16x16x32_bf16: A[m=lane&15][k=quad*8+j]; B[k=quad*8+j][n=lane&15];
// D: col=lane&15, row=quad*4+reg (HW-verified m89/m91/m120).
// State RAW fp32 + per-column (mean,rstd); readers apply affine lazily.
// Lb = pre-normed bf16 L [v | v+nv]; Cb = raw bf16 C — both ws-optional.

#define NROUNDS 32
#define NORM_EPS 1e-3f
#define LOSS_EPS 1e-8f

static constexpr int NV_CONST = 100000;
static constexpr int NG_CONST = 100;

typedef __attribute__((ext_vector_type(8))) short short8;
typedef __attribute__((ext_vector_type(4))) float f32x4;

__device__ __forceinline__ short f2bf(float f) {
    union { float f; unsigned u; } x; x.f = f;
    unsigned r = x.u + 0x7fffu + ((x.u >> 16) & 1u);   // RNE
    return (short)(r >> 16);
}
__device__ __forceinline__ float bf2f(short s) {
    union { unsigned u; float f; } x; x.u = ((unsigned)(unsigned short)s) << 16;
    return x.f;
}

// ---------------- setup kernels ----------------

__global__ void k_zero_i(int* __restrict__ p, int n) {
    int i = blockIdx.x * 256 + threadIdx.x;
    if (i < n) p[i] = 0;
}
__global__ void k_fill(float* __restrict__ p, int n, const float* __restrict__ vp) {
    int i = blockIdx.x * 256 + threadIdx.x;
    if (i < n) p[i] = *vp;
}
__global__ void k_fill_b(short* __restrict__ p, int n, const float* __restrict__ vp) {
    int i = blockIdx.x * 256 + threadIdx.x;
    if (i < n) p[i] = f2bf(*vp);
}
__global__ void k_copy_int(int* __restrict__ dst, const int* __restrict__ src, int n) {
    int i = blockIdx.x * 256 + threadIdx.x;
    if (i < n) dst[i] = src[i];
}
__global__ void k_init_stats(float* statC, float* statL, float* accumC, float* accumL,
                             float* loss_a, int* cnts) {
    int i = threadIdx.x;
    if (i < 160) {
        float v = (i < 80) ? 0.f : 1.f;   // identity norm
        statC[i] = v; statL[i] = v;
        accumC[i] = 0.f; accumL[i] = 0.f;
    }
    if (i == 0) { loss_a[0] = 0.f; cnts[0] = 0; cnts[1] = 0; }
}

__global__ void k_litrow(const int* __restrict__ lit_var, const int* __restrict__ lit_neg,
                         int* __restrict__ litrow, int* __restrict__ counts,
                         int ncell, int nv) {
    int i = blockIdx.x * 256 + threadIdx.x;
    if (i < ncell) {
        int r = lit_var[i] + lit_neg[i] * nv;
        litrow[i] = r;
        atomicAdd(&counts[r], 1);
    }
}

__launch_bounds__(1024)
__global__ void k_scan4(const int* __restrict__ counts, int* __restrict__ row_ptr,
                        int n, int total) {
    __shared__ int sd[1024];
    __shared__ int carry;
    int tid = threadIdx.x;
    if (tid == 0) carry = 0;
    __syncthreads();
    for (int base = 0; base < n; base += 4096) {
        int i0 = base + tid * 4;
        int a0 = (i0 + 0 < n) ? counts[i0 + 0] : 0;
        int a1 = (i0 + 1 < n) ? counts[i0 + 1] : 0;
        int a2 = (i0 + 2 < n) ? counts[i0 + 2] : 0;
        int a3 = (i0 + 3 < n) ? counts[i0 + 3] : 0;
        int s = a0 + a1 + a2 + a3;
        sd[tid] = s;
        __syncthreads();
        for (int off = 1; off < 1024; off <<= 1) {
            int t = (tid >= off) ? sd[tid - off] : 0;
            __syncthreads();
            sd[tid] += t;
            __syncthreads();
        }
        int excl = carry + sd[tid] - s;
        if (i0 + 0 < n) row_ptr[i0 + 0] = excl;
        if (i0 + 1 < n) row_ptr[i0 + 1] = excl + a0;
        if (i0 + 2 < n) row_ptr[i0 + 2] = excl + a0 + a1;
        if (i0 + 3 < n) row_ptr[i0 + 3] = excl + a0 + a1 + a2;
        __syncthreads();
        if (tid == 0) carry += sd[1023];
        __syncthreads();
    }
    if (tid == 0) row_ptr[n] = total;
}

__global__ void k_fill_csr(const int* __restrict__ litrow, const int* __restrict__ clause_idx,
                           int* __restrict__ cursor, int* __restrict__ cl_of, int ncell) {
    int i = blockIdx.x * 256 + threadIdx.x;
    if (i < ncell) {
        int r = litrow[i];
        int pos = atomicAdd(&cursor[r], 1);
        cl_of[pos] = clause_idx[i];
    }
}

// Wp frag t=(nb*KB+kb)*64+lane holds W[kb*32+quad*8+j][nb*16+(lane&15)], zero-padded.
__global__ void k_pack_w(const float* __restrict__ W, short* __restrict__ Wp,
                         int K, int N, int KB, int NB) {
    int t = blockIdx.x * 256 + threadIdx.x;
    int tot = NB * KB * 64;
    if (t >= tot) return;
    int lane = t & 63;
    int kb = (t >> 6) % KB;
    int nb = t / (64 * KB);
    int quad = lane >> 4, l15 = lane & 15;
    int n = nb * 16 + l15;
#pragma unroll
    for (int j = 0; j < 8; ++j) {
        int k = kb * 32 + quad * 8 + j;
        float f = (k < K && n < N) ? W[(size_t)k * N + n] : 0.f;
        Wp[(size_t)t * 8 + j] = f2bf(f);
    }
}

// ---------------- MFMA building blocks ----------------

template <int KB, int NB>
__device__ __forceinline__ void mfma_layer(const short* lds, int SK,
                                           const short8* __restrict__ Wp,
                                           f32x4* acc, int lane, int arow) {
    const int quad8 = (lane >> 4) * 8;
    short8 a[KB];
#pragma unroll
    for (int kb = 0; kb < KB; ++kb)
        a[kb] = *(const short8*)(lds + arow * SK + kb * 32 + quad8);
#pragma unroll
    for (int kb = 0; kb < KB; ++kb)
#pragma unroll
        for (int nb = 0; nb < NB; ++nb)
            acc[nb] = __builtin_amdgcn_mfma_f32_16x16x32_bf16(
                a[kb], Wp[(nb * KB + kb) * 64 + lane], acc[nb], 0, 0, 0);
}

// wave-private: writes only rows wr0..wr0+15 (same stripe the wave reads)
template <int NB>
__device__ __forceinline__ void write_hidden(short* ldsH, int SKH, const f32x4* acc,
                                             const float* __restrict__ bias,
                                             int l15, int quad, int wr0) {
#pragma unroll
    for (int nb = 0; nb < NB; ++nb) {
        int c = nb * 16 + l15;
        float bv = bias[c];
#pragma unroll
        for (int reg = 0; reg < 4; ++reg) {
            int row = wr0 + quad * 4 + reg;
            float v = acc[nb][reg] + bv;
            v = fminf(fmaxf(v, 0.f), 6.f);
            ldsH[row * SKH + c] = f2bf(v);
        }
    }
}

__device__ __forceinline__ void store_bf4(short* p, float a, float b, float c, float d) {
    short4 v; v.x = f2bf(a); v.y = f2bf(b); v.z = f2bf(c); v.w = f2bf(d);
    *(short4*)p = v;
}

// last-block stats finalize: mean/rstd from accum, reset accum+counter
__device__ __forceinline__ void stats_finalize(float* __restrict__ accum,
                                               float* __restrict__ stat,
                                               int* __restrict__ cnt, float Minv,
                                               int tid, int* slast) {
    __threadfence();
    __syncthreads();
    if (tid == 0) {
        int t = __hip_atomic_fetch_add(cnt, 1, __ATOMIC_ACQ_REL, __HIP_MEMORY_SCOPE_AGENT);
        *slast = (t == (int)gridDim.x - 1) ? 1 : 0;
    }
    __syncthreads();
    if (*slast) {
        if (tid < 80) {
            float m  = __hip_atomic_load(&accum[tid], __ATOMIC_RELAXED, __HIP_MEMORY_SCOPE_AGENT);
            float v2 = __hip_atomic_load(&accum[80 + tid], __ATOMIC_RELAXED, __HIP_MEMORY_SCOPE_AGENT);
            float mean = m * Minv;
            float var  = v2 * Minv - mean * mean;
            stat[tid] = mean;
            stat[80 + tid] = rsqrtf(var + NORM_EPS);
            accum[tid] = 0.f; accum[80 + tid] = 0.f;
        }
        if (tid == 0) *cnt = 0;
    }
}

// ---------------- fused C update ----------------
__launch_bounds__(256, 2)
__global__ void k_c_update(float* __restrict__ C, short* __restrict__ Cb,
                           const float* __restrict__ L,
                           const short* __restrict__ Lb, const int* __restrict__ litrow,
                           const float* __restrict__ scp,
                           const short8* __restrict__ W0p, const float* __restrict__ b0,
                           const short8* __restrict__ W1p, const float* __restrict__ b1,
                           float* __restrict__ statC, const float* __restrict__ statL,
                           float* __restrict__ accumC, int* __restrict__ cnt, float Minv,
                           int ncl, int nv) {
    constexpr int SK = 168;
    __shared__ short lds[64 * SK];
    __shared__ float sred[160], sC[160], sL[160];
    __shared__ int slast;
    const int lane = threadIdx.x, wy = threadIdx.y, tid = wy * 64 + lane;
    const int r0 = blockIdx.x * 64;
    const int rows = (ncl - r0 < 64) ? (ncl - r0) : 64;

    if (tid < 160) { sred[tid] = 0.f; sC[tid] = statC[tid]; sL[tid] = statL[tid]; }
    __syncthreads();

    const float s = *scp;
    for (int it = tid; it < 64 * 40; it += 256) {
        int lr = it / 40, q = it % 40;
        int c = r0 + ((lr < rows) ? lr : rows - 1);
        if (q < 20) {
            float4 v = ((const float4*)C)[(size_t)c * 20 + q];
            int col = 4 * q;
            store_bf4(lds + lr * SK + col,
                      (v.x - sC[col]) * sC[80 + col],
                      (v.y - sC[col + 1]) * sC[80 + col + 1],
                      (v.z - sC[col + 2]) * sC[80 + col + 2],
                      (v.w - sC[col + 3]) * sC[80 + col + 3]);
        } else {
            int qq = q - 20, b = c * 3, col = 4 * qq;
            int ra = litrow[b], rb = litrow[b + 1], rc = litrow[b + 2];
            float ax, ay, az, aw;
            if (Lb) {
                const short* pa = Lb + ((ra < nv) ? (size_t)ra * 160 : (size_t)(ra - nv) * 160 + 80) + col;
                const short* pb = Lb + ((rb < nv) ? (size_t)rb * 160 : (size_t)(rb - nv) * 160 + 80) + col;
                const short* pc = Lb + ((rc < nv) ? (size_t)rc * 160 : (size_t)(rc - nv) * 160 + 80) + col;
                short4 va = *(const short4*)pa, vb = *(const short4*)pb, vc = *(const short4*)pc;
                ax = bf2f(va.x) + bf2f(vb.x) + bf2f(vc.x);
                ay = bf2f(va.y) + bf2f(vb.y) + bf2f(vc.y);
                az = bf2f(va.z) + bf2f(vb.z) + bf2f(vc.z);
                aw = bf2f(va.w) + bf2f(vb.w) + bf2f(vc.w);
            } else {
                const float4* L4 = (const float4*)L;
                float4 va = L4[(size_t)ra * 20 + qq];
                float4 vb = L4[(size_t)rb * 20 + qq];
                float4 vc = L4[(size_t)rc * 20 + qq];
                ax = (va.x + vb.x + vc.x - 3.f * sL[col]) * sL[80 + col];
                ay = (va.y + vb.y + vc.y - 3.f * sL[col + 1]) * sL[80 + col + 1];
                az = (va.z + vb.z + vc.z - 3.f * sL[col + 2]) * sL[80 + col + 2];
                aw = (va.w + vb.w + vc.w - 3.f * sL[col + 3]) * sL[80 + col + 3];
            }
            store_bf4(lds + lr * SK + 80 + col, ax * s, ay * s, az * s, aw * s);
        }
    }
    __syncthreads();   // staging crosses stripes; everything after is wave-private

    const int quad = lane >> 4, l15 = lane & 15, wr0 = wy * 16, arow = wr0 + l15;

    f32x4 acc[10];
#pragma unroll
    for (int nb = 0; nb < 10; ++nb) { f32x4 z = {0.f, 0.f, 0.f, 0.f}; acc[nb] = z; }
    mfma_layer<5, 10>(lds, SK, W0p, acc, lane, arow);
    write_hidden<10>(lds, SK, acc, b0, l15, quad, wr0);

    f32x4 acc2[5];
#pragma unroll
    for (int nb = 0; nb < 5; ++nb) { f32x4 z = {0.f, 0.f, 0.f, 0.f}; acc2[nb] = z; }
    mfma_layer<5, 5>(lds, SK, W1p, acc2, lane, arow);

#pragma unroll
    for (int nb = 0; nb < 5; ++nb) {
        int cc = nb * 16 + l15;
        float bv = b1[cc];
        float s1 = 0.f, s2 = 0.f;
#pragma unroll
        for (int reg = 0; reg < 4; ++reg) {
            int lr = wr0 + quad * 4 + reg;
            if (lr < rows) {
                float v = acc2[nb][reg] + bv;
                C[(size_t)(r0 + lr) * 80 + cc] = v;
                if (Cb) Cb[(size_t)(r0 + lr) * 80 + cc] = f2bf(v);
                s1 += v; s2 += v * v;
            }
        }
        s1 += __shfl_xor(s1, 16); s1 += __shfl_xor(s1, 32);
        s2 += __shfl_xor(s2, 16); s2 += __shfl_xor(s2, 32);
        if (quad == 0) { atomicAdd(&sred[cc], s1); atomicAdd(&sred[80 + cc], s2); }
    }
    __syncthreads();
    if (tid < 160) atomicAdd(&accumC[tid], sred[tid]);
    stats_finalize(accumC, statC, cnt, Minv, tid, &slast);
}

// ---------------- fused L update ----------------
// paired rows [vb,vb+32) u [vb+nv,vb+nv+32); lane-major gather with LDS cl lists.
__launch_bounds__(256, 2)
__global__ void k_l_update(float* __restrict__ L, const short* __restrict__ Lb,
                           const float* __restrict__ C, const short* __restrict__ Cb,
                           const int* __restrict__ row_ptr, const int* __restrict__ cl_of,
                           const float* __restrict__ scp,
                           const short8* __restrict__ W0p, const float* __restrict__ b0,
                           const short8* __restrict__ W1p, const float* __restrict__ b1,
                           const float* __restrict__ statC, float* __restrict__ statL,
                           float* __restrict__ accumL, int* __restrict__ cnt, float Minv,
                           int nv) {
    constexpr int SK = 264;
    __shared__ short lds[64 * SK];             // input K=256, then hidden 240+16pad
    __shared__ int scl[1024];
    __shared__ float sred[160], sC[160], sL[160];
    __shared__ int slast;
    const int lane = threadIdx.x, wy = threadIdx.y, tid = wy * 64 + lane;
    const int vb = blockIdx.x * 32;

    if (tid < 160) { sred[tid] = 0.f; sC[tid] = statC[tid]; sL[tid] = statL[tid]; }

    // stage this block's two contiguous cl_of windows into LDS
    const int b0r = row_ptr[vb],      e0r = row_ptr[vb + 32];
    const int b1r = row_ptr[vb + nv], e1r = row_ptr[vb + nv + 32];
    const int s0 = e0r - b0r, s1 = e1r - b1r;
    const bool fits = (s0 + s1) <= 1024;
    if (fits) {
        for (int i = tid; i < s0; i += 256) scl[i] = cl_of[b0r + i];
        for (int i = tid; i < s1; i += 256) scl[s0 + i] = cl_of[b1r + i];
    }
    __syncthreads();

    const float s = *scp;
    // ---- coalesced copies: seg0 cols 0..79, seg2 cols 160..239, pad 240..255 ----
    for (int it = tid; it < 64 * 44; it += 256) {
        int lr = it / 44, q = it % 44;
        short* dst = lds + lr * SK;
        if (q >= 40) {
            short4 z; z.x = 0; z.y = 0; z.z = 0; z.w = 0;
            *(short4*)(dst + 240 + 4 * (q - 40)) = z;
        } else if (Lb) {
            size_t base = (lr < 32) ? (size_t)(vb + lr) * 160 : (size_t)(vb + lr - 32) * 160;
            int half0 = (lr < 32) ? 0 : 80;
            if (q < 20) {
                *(short4*)(dst + 4 * q) = *(const short4*)(Lb + base + half0 + 4 * q);
            } else {
                int qq = q - 20;
                *(short4*)(dst + 160 + 4 * qq) = *(const short4*)(Lb + base + (80 - half0) + 4 * qq);
            }
        } else {
            int r = (lr < 32) ? vb + lr : vb + nv + (lr - 32);
            if (q < 20) {
                int col = 4 * q;
                float4 v = ((const float4*)L)[(size_t)r * 20 + q];
                store_bf4(dst + col,
                          (v.x - sL[col]) * sL[80 + col],
                          (v.y - sL[col + 1]) * sL[80 + col + 1],
                          (v.z - sL[col + 2]) * sL[80 + col + 2],
                          (v.w - sL[col + 3]) * sL[80 + col + 3]);
            } else {
                int qq = q - 20, col = 4 * qq;
                int fr = (r < nv) ? r + nv : r - nv;
                float4 v = ((const float4*)L)[(size_t)fr * 20 + qq];
                store_bf4(dst + 160 + col,
                          (v.x - sL[col]) * sL[80 + col],
                          (v.y - sL[col + 1]) * sL[80 + col + 1],
                          (v.z - sL[col + 2]) * sL[80 + col + 2],
                          (v.w - sL[col + 3]) * sL[80 + col + 3]);
            }
        }
    }
    // ---- gather: lane = row (64 independent chains/wave), 16B chunks ----
    {
        const int row = lane;
        const int r = (row < 32) ? vb + row : vb + nv + (row - 32);
        const int p0 = row_ptr[r], p1 = row_ptr[r + 1];
        const int deg = p1 - p0;
        const float nf = (float)deg;
        const int loff = (row < 32) ? (p0 - b0r) : (s0 + (p0 - b1r));
        short* dst = lds + row * SK + 80;
        for (int c8 = wy; c8 < 10; c8 += 4) {
            float ax[8];
#pragma unroll
            for (int j = 0; j < 8; ++j) ax[j] = 0.f;
            if (Cb) {
                const short8* Cb8 = (const short8*)Cb;
                int i = 0;
                for (; i + 2 <= deg; i += 2) {
                    int ca = fits ? scl[loff + i]     : cl_of[p0 + i];
                    int cb = fits ? scl[loff + i + 1] : cl_of[p0 + i + 1];
                    short8 v0 = Cb8[(size_t)ca * 10 + c8];
                    short8 v1 = Cb8[(size_t)cb * 10 + c8];
#pragma unroll
                    for (int j = 0; j < 8; ++j) ax[j] += bf2f(v0[j]) + bf2f(v1[j]);
                }
                if (i < deg) {
                    int ca = fits ? scl[loff + i] : cl_of[p0 + i];
                    short8 v0 = Cb8[(size_t)ca * 10 + c8];
#pragma unroll
                    for (int j = 0; j < 8; ++j) ax[j] += bf2f(v0[j]);
                }
            } else {
                const float4* C4 = (const float4*)C;
                for (int i = 0; i < deg; ++i) {
                    int ca = fits ? scl[loff + i] : cl_of[p0 + i];
                    float4 va = C4[(size_t)ca * 20 + c8 * 2];
                    float4 vb2 = C4[(size_t)ca * 20 + c8 * 2 + 1];
                    ax[0] += va.x;  ax[1] += va.y;  ax[2] += va.z;  ax[3] += va.w;
                    ax[4] += vb2.x; ax[5] += vb2.y; ax[6] += vb2.z; ax[7] += vb2.w;
                }
            }
            short8 o;
#pragma unroll
            for (int j = 0; j < 8; ++j) {
                int col = c8 * 8 + j;
                o[j] = f2bf((ax[j] - nf * sC[col]) * sC[80 + col] * s);
            }
            *(short8*)(dst + c8 * 8) = o;
        }
    }
    __syncthreads();   // staging crosses stripes; rest is wave-private

    const int quad = lane >> 4, l15 = lane & 15, wr0 = wy * 16, arow = wr0 + l15;

    f32x4 acc[15];
#pragma unroll
    for (int nb = 0; nb < 15; ++nb) { f32x4 z = {0.f, 0.f, 0.f, 0.f}; acc[nb] = z; }
    mfma_layer<8, 15>(lds, SK, W0p, acc, lane, arow);
    write_hidden<15>(lds, SK, acc, b0, l15, quad, wr0);
    {   // zero-pad hidden cols 240..255 of OWN stripe (wave-private)
        int row = wr0 + (lane >> 2);
        int c = 240 + (lane & 3) * 4;
        short4 z; z.x = 0; z.y = 0; z.z = 0; z.w = 0;
        *(short4*)(lds + row * SK + c) = z;
    }

    f32x4 acc2[5];
#pragma unroll
    for (int nb = 0; nb < 5; ++nb) { f32x4 z = {0.f, 0.f, 0.f, 0.f}; acc2[nb] = z; }
    mfma_layer<8, 5>(lds, SK, W1p, acc2, lane, arow);

#pragma unroll
    for (int nb = 0; nb < 5; ++nb) {
        int cc = nb * 16 + l15;
        float bv = b1[cc];
        float s1 = 0.f, s2 = 0.f;
#pragma unroll
        for (int reg = 0; reg < 4; ++reg) {
            int lr = wr0 + quad * 4 + reg;
            int rabs = (lr < 32) ? vb + lr : vb + nv + (lr - 32);
            float v = acc2[nb][reg] + bv;
            L[(size_t)rabs * 80 + cc] = v;
            s1 += v; s2 += v * v;
        }
        s1 += __shfl_xor(s1, 16); s1 += __shfl_xor(s1, 32);
        s2 += __shfl_xor(s2, 16); s2 += __shfl_xor(s2, 32);
        if (quad == 0) { atomicAdd(&sred[cc], s1); atomicAdd(&sred[80 + cc], s2); }
    }
    __syncthreads();
    if (tid < 160) atomicAdd(&accumL[tid], sred[tid]);
    stats_finalize(accumL, statL, cnt, Minv, tid, &slast);
}

// ---------------- fused V head (4 layers, single LDS buffer) ----------------
__launch_bounds__(256, 2)
__global__ void k_v_head(const float* __restrict__ L, const float* __restrict__ statL,
                         const short8* __restrict__ W0p, const float* __restrict__ b0,
                         const short8* __restrict__ W1p, const float* __restrict__ b1,
                         const short8* __restrict__ W2p, const float* __restrict__ b2,
                         const float* __restrict__ W3, const float* __restrict__ b3,
                         float* __restrict__ logits, short* __restrict__ Lb, int nv) {
    constexpr int SK = 168;
    __shared__ short lds[64 * SK];
    __shared__ float sW3[160], sL[160];
    const int lane = threadIdx.x, wy = threadIdx.y, tid = wy * 64 + lane;
    const int v0 = blockIdx.x * 64;
    const int cnt = (nv - v0 < 64) ? (nv - v0) : 64;

    if (tid < 160) { sW3[tid] = W3[tid]; sL[tid] = statL[tid]; }
    __syncthreads();

    for (int it = tid; it < 64 * 40; it += 256) {
        int lr = it / 40, q = it % 40;
        int v = v0 + ((lr < cnt) ? lr : cnt - 1);
        int qq = (q < 20) ? q : q - 20;
        int rr = (q < 20) ? v : v + nv;
        int col = 4 * q, scol = 4 * qq;
        float4 x = ((const float4*)L)[(size_t)rr * 20 + qq];
        short4 o;
        o.x = f2bf((x.x - sL[scol]) * sL[80 + scol]);
        o.y = f2bf((x.y - sL[scol + 1]) * sL[80 + scol + 1]);
        o.z = f2bf((x.z - sL[scol + 2]) * sL[80 + scol + 2]);
        o.w = f2bf((x.w - sL[scol + 3]) * sL[80 + scol + 3]);
        *(short4*)(lds + lr * SK + col) = o;
        if (Lb && lr < cnt) *(short4*)(Lb + (size_t)v * 160 + col) = o;
    }
    __syncthreads();   // staging crosses stripes

    const int quad = lane >> 4, l15 = lane & 15, wr0 = wy * 16, arow = wr0 + l15;

    f32x4 acc[10];
#pragma unroll
    for (int nb = 0; nb < 10; ++nb) { f32x4 z = {0.f, 0.f, 0.f, 0.f}; acc[nb] = z; }
    mfma_layer<5, 10>(lds, SK, W0p, acc, lane, arow);
    write_hidden<10>(lds, SK, acc, b0, l15, quad, wr0);

#pragma unroll
    for (int nb = 0; nb < 10; ++nb) { f32x4 z = {0.f, 0.f, 0.f, 0.f}; acc[nb] = z; }
    mfma_layer<5, 10>(lds, SK, W1p, acc, lane, arow);
    write_hidden<10>(lds, SK, acc, b1, l15, quad, wr0);

#pragma unroll
    for (int nb = 0; nb < 10; ++nb) { f32x4 z = {0.f, 0.f, 0.f, 0.f}; acc[nb] = z; }
    mfma_layer<5, 10>(lds, SK, W2p, acc, lane, arow);
    write_hidden<10>(lds, SK, acc, b2, l15, quad, wr0);
    __syncthreads();   // final dot reads across stripes

    int lrow = tid >> 2, t4 = tid & 3;
    float v = 0.f;
    for (int c = t4; c < 160; c += 4) v += bf2f(lds[lrow * SK + c]) * sW3[c];
    v += __shfl_down(v, 2, 4);
    v += __shfl_down(v, 1, 4);
    if (t4 == 0 && lrow < cnt) logits[v0 + lrow] = v + b3[0];
}

// ---------------- loss ----------------
__device__ __forceinline__ float softplusf(float x) {
    return fmaxf(x, 0.f) + log1pf(expf(-fabsf(x)));
}

__global__ void k_loss(const float* __restrict__ logits, const int* __restrict__ lit_var,
                       const int* __restrict__ lit_neg, float* __restrict__ loss_acc,
                       int cpg) {
    const int g = blockIdx.x;
    const int tid = threadIdx.x;
    float part = 0.f;
    int cend = (g + 1) * cpg;
    for (int c = g * cpg + tid; c < cend; c += 256) {
        float cs = 0.f;
#pragma unroll
        for (int t = 0; t < 3; ++t) {
            int i = c * 3 + t;
            float sign = lit_neg[i] ? -1.f : 1.f;
            cs += softplusf(logits[lit_var[i]] * sign);
        }
        float vc = expf(-cs);
        part += vc * (-log1pf(LOSS_EPS - vc));
    }
    __shared__ float red[256];
    red[tid] = part;
    __syncthreads();
    for (int s = 128; s > 0; s >>= 1) {
        if (tid < s) red[tid] += red[tid + s];
        __syncthreads();
    }
    if (tid == 0) atomicAdd(loss_acc, sqrtf(red[0] + 1e-6f));
}

__global__ void k_output(float* __restrict__ dout, const float* __restrict__ logits,
                         const float* __restrict__ loss_acc, int nv) {
    int i = blockIdx.x * 256 + threadIdx.x;
    if (i < nv) dout[i] = logits[i];
    else if (i == nv) dout[i] = loss_acc[0] * (1.f / (float)NROUNDS);
}

// ---------------- host ----------------

extern "C" void kernel_launch(void* const* d_in, const int* in_sizes, int n_in,
                              void* d_out, int out_size, void* d_ws, size_t ws_size,
                              hipStream_t stream) {
    const int* lit_var    = (const int*)d_in[0];
    const int* lit_neg    = (const int*)d_in[1];
    const int* clause_idx = (const int*)d_in[2];
    const float* Lscale = (const float*)d_in[7];
    const float* Cscale = (const float*)d_in[8];
    const float* LCs    = (const float*)d_in[9];
    const float* CLs    = (const float*)d_in[10];
    const float* LuW0 = (const float*)d_in[11]; const float* Lub0 = (const float*)d_in[12];
    const float* LuW1 = (const float*)d_in[13]; const float* Lub1 = (const float*)d_in[14];
    const float* CuW0 = (const float*)d_in[15]; const float* Cub0 = (const float*)d_in[16];
    const float* CuW1 = (const float*)d_in[17]; const float* Cub1 = (const float*)d_in[18];
    const float* VsW0 = (const float*)d_in[19]; const float* Vsb0 = (const float*)d_in[20];
    const float* VsW1 = (const float*)d_in[21]; const float* Vsb1 = (const float*)d_in[22];
    const float* VsW2 = (const float*)d_in[23]; const float* Vsb2 = (const float*)d_in[24];
    const float* VsW3 = (const float*)d_in[25]; const float* Vsb3 = (const float*)d_in[26];

    const int ncell = in_sizes[0];          // 1,260,000
    const int ncl   = in_sizes[3];          // 420,000
    const int nv    = NV_CONST;
    const int nl    = 2 * nv;
    const int ng    = NG_CONST;

    size_t off = 0;
    auto A = [&](size_t bytes) -> void* {
        void* q = (char*)d_ws + off;
        off = (off + bytes + 255) & ~(size_t)255;
        return q;
    };
    float* L      = (float*)A((size_t)nl  * 80 * 4);   // raw L state
    float* C      = (float*)A((size_t)ncl * 80 * 4);   // raw C state
    float* logits = (float*)A((size_t)nv * 4);
    float* statC  = (float*)A(160 * 4);
    float* statL  = (float*)A(160 * 4);
    float* accumC = (float*)A(160 * 4);
    float* accumL = (float*)A(160 * 4);
    float* loss_a = (float*)A(256);
    int*   cnts   = (int*)A(256);
    int* litrow  = (int*)A((size_t)ncell * 4);
    int* row_ptr = (int*)A((size_t)(nl + 1) * 4);
    int* tmp     = (int*)A((size_t)nl * 4);
    int* cl_of   = (int*)A((size_t)ncell * 4);
    short* CuW0p = (short*)A((size_t)10 * 5 * 64 * 16);
    short* CuW1p = (short*)A((size_t)5  * 5 * 64 * 16);
    short* LuW0p = (short*)A((size_t)15 * 8 * 64 * 16);
    short* LuW1p = (short*)A((size_t)5  * 8 * 64 * 16);
    short* VsW0p = (short*)A((size_t)10 * 5 * 64 * 16);
    short* VsW1p = (short*)A((size_t)10 * 5 * 64 * 16);
    short* VsW2p = (short*)A((size_t)10 * 5 * 64 * 16);
    size_t lb_bytes = (size_t)nv * 160 * 2;
    short* Lb = nullptr;
    if (off + lb_bytes + 256 <= ws_size) Lb = (short*)A(lb_bytes);
    size_t cb_bytes = (size_t)ncl * 80 * 2;
    short* Cb = nullptr;
    if (off + cb_bytes + 256 <= ws_size) Cb = (short*)A(cb_bytes);

    const dim3 B64x4(64, 4, 1);

    // ---- setup ----
    k_zero_i<<<(nl + 255) / 256, 256, 0, stream>>>(tmp, nl);
    k_init_stats<<<1, 192, 0, stream>>>(statC, statL, accumC, accumL, loss_a, cnts);
    k_litrow<<<(ncell + 255) / 256, 256, 0, stream>>>(lit_var, lit_neg, litrow, tmp, ncell, nv);
    k_scan4<<<1, 1024, 0, stream>>>(tmp, row_ptr, nl, ncell);
    k_copy_int<<<(nl + 255) / 256, 256, 0, stream>>>(tmp, row_ptr, nl);
    k_fill_csr<<<(ncell + 255) / 256, 256, 0, stream>>>(litrow, clause_idx, tmp, cl_of, ncell);
    k_fill<<<(nl * 80 + 255) / 256, 256, 0, stream>>>(L, nl * 80, Lscale);
    k_fill<<<(ncl * 80 + 255) / 256, 256, 0, stream>>>(C, ncl * 80, Cscale);
    if (Lb) k_fill_b<<<(nv * 160 + 255) / 256, 256, 0, stream>>>(Lb, nv * 160, Lscale);
    if (Cb) k_fill_b<<<(ncl * 80 + 255) / 256, 256, 0, stream>>>(Cb, ncl * 80, Cscale);
    k_pack_w<<<(10 * 5 * 64 + 255) / 256, 256, 0, stream>>>(CuW0, CuW0p, 160, 160, 5, 10);
    k_pack_w<<<(5  * 5 * 64 + 255) / 256, 256, 0, stream>>>(CuW1, CuW1p, 160, 80, 5, 5);
    k_pack_w<<<(15 * 8 * 64 + 255) / 256, 256, 0, stream>>>(LuW0, LuW0p, 240, 240, 8, 15);
    k_pack_w<<<(5  * 8 * 64 + 255) / 256, 256, 0, stream>>>(LuW1, LuW1p, 240, 80, 8, 5);
    k_pack_w<<<(10 * 5 * 64 + 255) / 256, 256, 0, stream>>>(VsW0, VsW0p, 160, 160, 5, 10);
    k_pack_w<<<(10 * 5 * 64 + 255) / 256, 256, 0, stream>>>(VsW1, VsW1p, 160, 160, 5, 10);
    k_pack_w<<<(10 * 5 * 64 + 255) / 256, 256, 0, stream>>>(VsW2, VsW2p, 160, 160, 5, 10);

    const int cblk = (ncl + 63) / 64;       // 6563
    const int lblk = nv / 32;               // 3125
    const int vblk = (nv + 63) / 64;        // 1563

    for (int r = 0; r < NROUNDS; ++r) {
        k_c_update<<<cblk, B64x4, 0, stream>>>(
            C, Cb, L, Lb, litrow, LCs, (const short8*)CuW0p, Cub0, (const short8*)CuW1p, Cub1,
            statC, statL, accumC, cnts + 0, 1.f / (float)ncl, ncl, nv);
        k_l_update<<<lblk, B64x4, 0, stream>>>(
            L, Lb, C, Cb, row_ptr, cl_of, CLs, (const short8*)LuW0p, Lub0,
            (const short8*)LuW1p, Lub1, statC, statL, accumL, cnts + 1, 1.f / (float)nl, nv);
        k_v_head<<<vblk, B64x4, 0, stream>>>(
            L, statL, (const short8*)VsW0p, Vsb0, (const short8*)VsW1p, Vsb1,
            (const short8*)VsW2p, Vsb2, VsW3, Vsb3, logits, Lb, nv);
        k_loss<<<ng, 256, 0, stream>>>(logits, lit_var, lit_neg, loss_a, ncl / ng);
    }

    k_output<<<(nv + 1 + 255) / 256, 256, 0, stream>>>((float*)d_out, logits, loss_a, nv);
}

// Round 7
// 19616.104 us; speedup vs baseline: 3.0286x; 3.0286x over previous
//
#include <hip/hip_runtime.h>
#include <math.h>

// SimpleNeuroSAT on MI355X — round 6: revert round-5 regressions (cross-block
// stats fusion, lane-major gather); split CSR gather into standalone high-TLP
// kernel writing CLb (bf16). l_update becomes a pure coalesced MLP kernel.
// Structure relied on: clause c owns cells 3c..3c+2, graphs contiguous, n_vars=100000.
// MFMA 16x16x32_bf16: A[m=lane&15][k=quad*8+j]; B[k=quad*8+j][n=lane&15];
// D: col=lane&15, row=quad*4+reg (HW-verified m89/m91/m120).
// State RAW fp32 + per-column (mean,rstd); readers apply affine lazily.
// Optional ws buffers (null-fallbacks everywhere): CLb (gather split), Cb, Lb.

#define NROUNDS 32
#define NORM_EPS 1e-3f
#define LOSS_EPS 1e-8f

static constexpr int NV_CONST = 100000;
static constexpr int NG_CONST = 100;

typedef __attribute__((ext_vector_type(8))) short short8;
typedef __attribute__((ext_vector_type(4))) float f32x4;

__device__ __forceinline__ short f2bf(float f) {
    union { float f; unsigned u; } x; x.f = f;
    unsigned r = x.u + 0x7fffu + ((x.u >> 16) & 1u);   // RNE
    return (short)(r >> 16);
}
__device__ __forceinline__ float bf2f(short s) {
    union { unsigned u; float f; } x; x.u = ((unsigned)(unsigned short)s) << 16;
    return x.f;
}

// ---------------- setup kernels ----------------

__global__ void k_zero_i(int* __restrict__ p, int n) {
    int i = blockIdx.x * 256 + threadIdx.x;
    if (i < n) p[i] = 0;
}
__global__ void k_fill(float* __restrict__ p, int n, const float* __restrict__ vp) {
    int i = blockIdx.x * 256 + threadIdx.x;
    if (i < n) p[i] = *vp;
}
__global__ void k_fill_b(short* __restrict__ p, int n, const float* __restrict__ vp) {
    int i = blockIdx.x * 256 + threadIdx.x;
    if (i < n) p[i] = f2bf(*vp);
}
__global__ void k_copy_int(int* __restrict__ dst, const int* __restrict__ src, int n) {
    int i = blockIdx.x * 256 + threadIdx.x;
    if (i < n) dst[i] = src[i];
}
__global__ void k_init_stats(float* statC, float* statL, float* accumC, float* accumL,
                             float* loss_a) {
    int i = threadIdx.x;
    if (i < 160) {
        float v = (i < 80) ? 0.f : 1.f;   // identity norm
        statC[i] = v; statL[i] = v;
        accumC[i] = 0.f; accumL[i] = 0.f;
    }
    if (i == 0) loss_a[0] = 0.f;
}

__global__ void k_litrow(const int* __restrict__ lit_var, const int* __restrict__ lit_neg,
                         int* __restrict__ litrow, int* __restrict__ counts,
                         int ncell, int nv) {
    int i = blockIdx.x * 256 + threadIdx.x;
    if (i < ncell) {
        int r = lit_var[i] + lit_neg[i] * nv;
        litrow[i] = r;
        atomicAdd(&counts[r], 1);
    }
}

__launch_bounds__(1024)
__global__ void k_scan4(const int* __restrict__ counts, int* __restrict__ row_ptr,
                        int n, int total) {
    __shared__ int sd[1024];
    __shared__ int carry;
    int tid = threadIdx.x;
    if (tid == 0) carry = 0;
    __syncthreads();
    for (int base = 0; base < n; base += 4096) {
        int i0 = base + tid * 4;
        int a0 = (i0 + 0 < n) ? counts[i0 + 0] : 0;
        int a1 = (i0 + 1 < n) ? counts[i0 + 1] : 0;
        int a2 = (i0 + 2 < n) ? counts[i0 + 2] : 0;
        int a3 = (i0 + 3 < n) ? counts[i0 + 3] : 0;
        int s = a0 + a1 + a2 + a3;
        sd[tid] = s;
        __syncthreads();
        for (int off = 1; off < 1024; off <<= 1) {
            int t = (tid >= off) ? sd[tid - off] : 0;
            __syncthreads();
            sd[tid] += t;
            __syncthreads();
        }
        int excl = carry + sd[tid] - s;
        if (i0 + 0 < n) row_ptr[i0 + 0] = excl;
        if (i0 + 1 < n) row_ptr[i0 + 1] = excl + a0;
        if (i0 + 2 < n) row_ptr[i0 + 2] = excl + a0 + a1;
        if (i0 + 3 < n) row_ptr[i0 + 3] = excl + a0 + a1 + a2;
        __syncthreads();
        if (tid == 0) carry += sd[1023];
        __syncthreads();
    }
    if (tid == 0) row_ptr[n] = total;
}

__global__ void k_fill_csr(const int* __restrict__ litrow, const int* __restrict__ clause_idx,
                           int* __restrict__ cursor, int* __restrict__ cl_of, int ncell) {
    int i = blockIdx.x * 256 + threadIdx.x;
    if (i < ncell) {
        int r = litrow[i];
        int pos = atomicAdd(&cursor[r], 1);
        cl_of[pos] = clause_idx[i];
    }
}

// Wp frag t=(nb*KB+kb)*64+lane holds W[kb*32+quad*8+j][nb*16+(lane&15)], zero-padded.
__global__ void k_pack_w(const float* __restrict__ W, short* __restrict__ Wp,
                         int K, int N, int KB, int NB) {
    int t = blockIdx.x * 256 + threadIdx.x;
    int tot = NB * KB * 64;
    if (t >= tot) return;
    int lane = t & 63;
    int kb = (t >> 6) % KB;
    int nb = t / (64 * KB);
    int quad = lane >> 4, l15 = lane & 15;
    int n = nb * 16 + l15;
#pragma unroll
    for (int j = 0; j < 8; ++j) {
        int k = kb * 32 + quad * 8 + j;
        float f = (k < K && n < N) ? W[(size_t)k * N + n] : 0.f;
        Wp[(size_t)t * 8 + j] = f2bf(f);
    }
}

// ---------------- MFMA building blocks ----------------

template <int KB, int NB>
__device__ __forceinline__ void mfma_layer(const short* lds, int SK,
                                           const short8* __restrict__ Wp,
                                           f32x4* acc, int lane, int arow) {
    const int quad8 = (lane >> 4) * 8;
    short8 a[KB];
#pragma unroll
    for (int kb = 0; kb < KB; ++kb)
        a[kb] = *(const short8*)(lds + arow * SK + kb * 32 + quad8);
#pragma unroll
    for (int kb = 0; kb < KB; ++kb)
#pragma unroll
        for (int nb = 0; nb < NB; ++nb)
            acc[nb] = __builtin_amdgcn_mfma_f32_16x16x32_bf16(
                a[kb], Wp[(nb * KB + kb) * 64 + lane], acc[nb], 0, 0, 0);
}

// wave-private: writes only rows wr0..wr0+15 (same stripe the wave reads)
template <int NB>
__device__ __forceinline__ void write_hidden(short* ldsH, int SKH, const f32x4* acc,
                                             const float* __restrict__ bias,
                                             int l15, int quad, int wr0) {
#pragma unroll
    for (int nb = 0; nb < NB; ++nb) {
        int c = nb * 16 + l15;
        float bv = bias[c];
#pragma unroll
        for (int reg = 0; reg < 4; ++reg) {
            int row = wr0 + quad * 4 + reg;
            float v = acc[nb][reg] + bv;
            v = fminf(fmaxf(v, 0.f), 6.f);
            ldsH[row * SKH + c] = f2bf(v);
        }
    }
}

__device__ __forceinline__ void store_bf4(short* p, float a, float b, float c, float d) {
    short4 v; v.x = f2bf(a); v.y = f2bf(b); v.z = f2bf(c); v.w = f2bf(d);
    *(short4*)p = v;
}

// ---------------- fused C update (round-4 form) ----------------
__launch_bounds__(256, 2)
__global__ void k_c_update(float* __restrict__ C, short* __restrict__ Cb,
                           const float* __restrict__ L,
                           const short* __restrict__ Lb, const int* __restrict__ litrow,
                           const float* __restrict__ scp,
                           const short8* __restrict__ W0p, const float* __restrict__ b0,
                           const short8* __restrict__ W1p, const float* __restrict__ b1,
                           const float* __restrict__ statC, const float* __restrict__ statL,
                           float* __restrict__ accumC, int ncl, int nv) {
    constexpr int SK = 168;
    __shared__ short lds[64 * SK];
    __shared__ float sred[160], sC[160], sL[160];
    const int lane = threadIdx.x, wy = threadIdx.y, tid = wy * 64 + lane;
    const int r0 = blockIdx.x * 64;
    const int rows = (ncl - r0 < 64) ? (ncl - r0) : 64;

    if (tid < 160) { sred[tid] = 0.f; sC[tid] = statC[tid]; sL[tid] = statL[tid]; }
    __syncthreads();

    const float s = *scp;
    for (int it = tid; it < 64 * 40; it += 256) {
        int lr = it / 40, q = it % 40;
        int c = r0 + ((lr < rows) ? lr : rows - 1);
        if (q < 20) {
            float4 v = ((const float4*)C)[(size_t)c * 20 + q];
            int col = 4 * q;
            store_bf4(lds + lr * SK + col,
                      (v.x - sC[col]) * sC[80 + col],
                      (v.y - sC[col + 1]) * sC[80 + col + 1],
                      (v.z - sC[col + 2]) * sC[80 + col + 2],
                      (v.w - sC[col + 3]) * sC[80 + col + 3]);
        } else {
            int qq = q - 20, b = c * 3, col = 4 * qq;
            int ra = litrow[b], rb = litrow[b + 1], rc = litrow[b + 2];
            float ax, ay, az, aw;
            if (Lb) {
                const short* pa = Lb + ((ra < nv) ? (size_t)ra * 160 : (size_t)(ra - nv) * 160 + 80) + col;
                const short* pb = Lb + ((rb < nv) ? (size_t)rb * 160 : (size_t)(rb - nv) * 160 + 80) + col;
                const short* pc = Lb + ((rc < nv) ? (size_t)rc * 160 : (size_t)(rc - nv) * 160 + 80) + col;
                short4 va = *(const short4*)pa, vb = *(const short4*)pb, vc = *(const short4*)pc;
                ax = bf2f(va.x) + bf2f(vb.x) + bf2f(vc.x);
                ay = bf2f(va.y) + bf2f(vb.y) + bf2f(vc.y);
                az = bf2f(va.z) + bf2f(vb.z) + bf2f(vc.z);
                aw = bf2f(va.w) + bf2f(vb.w) + bf2f(vc.w);
            } else {
                const float4* L4 = (const float4*)L;
                float4 va = L4[(size_t)ra * 20 + qq];
                float4 vb = L4[(size_t)rb * 20 + qq];
                float4 vc = L4[(size_t)rc * 20 + qq];
                ax = (va.x + vb.x + vc.x - 3.f * sL[col]) * sL[80 + col];
                ay = (va.y + vb.y + vc.y - 3.f * sL[col + 1]) * sL[80 + col + 1];
                az = (va.z + vb.z + vc.z - 3.f * sL[col + 2]) * sL[80 + col + 2];
                aw = (va.w + vb.w + vc.w - 3.f * sL[col + 3]) * sL[80 + col + 3];
            }
            store_bf4(lds + lr * SK + 80 + col, ax * s, ay * s, az * s, aw * s);
        }
    }
    __syncthreads();   // staging crosses stripes; everything after is wave-private

    const int quad = lane >> 4, l15 = lane & 15, wr0 = wy * 16, arow = wr0 + l15;

    f32x4 acc[10];
#pragma unroll
    for (int nb = 0; nb < 10; ++nb) { f32x4 z = {0.f, 0.f, 0.f, 0.f}; acc[nb] = z; }
    mfma_layer<5, 10>(lds, SK, W0p, acc, lane, arow);
    write_hidden<10>(lds, SK, acc, b0, l15, quad, wr0);

    f32x4 acc2[5];
#pragma unroll
    for (int nb = 0; nb < 5; ++nb) { f32x4 z = {0.f, 0.f, 0.f, 0.f}; acc2[nb] = z; }
    mfma_layer<5, 5>(lds, SK, W1p, acc2, lane, arow);

#pragma unroll
    for (int nb = 0; nb < 5; ++nb) {
        int cc = nb * 16 + l15;
        float bv = b1[cc];
        float s1 = 0.f, s2 = 0.f;
#pragma unroll
        for (int reg = 0; reg < 4; ++reg) {
            int lr = wr0 + quad * 4 + reg;
            if (lr < rows) {
                float v = acc2[nb][reg] + bv;
                C[(size_t)(r0 + lr) * 80 + cc] = v;
                if (Cb) Cb[(size_t)(r0 + lr) * 80 + cc] = f2bf(v);
                s1 += v; s2 += v * v;
            }
        }
        s1 += __shfl_xor(s1, 16); s1 += __shfl_xor(s1, 32);
        s2 += __shfl_xor(s2, 16); s2 += __shfl_xor(s2, 32);
        if (quad == 0) { atomicAdd(&sred[cc], s1); atomicAdd(&sred[80 + cc], s2); }
    }
    __syncthreads();
    if (tid < 160) atomicAdd(&accumC[tid], sred[tid]);
}

// ---------------- standalone CL gather: high-TLP, coalesced ----------------
// thread = (row r, 8B chunk q of 20). The 20 chunk-threads of a row read each
// clause row as one contiguous 160B line. Writes CLb = bf16 normalized message.
__global__ void k_cl_gather(const float* __restrict__ C, const short* __restrict__ Cb,
                            const int* __restrict__ row_ptr, const int* __restrict__ cl_of,
                            const float* __restrict__ scp, const float* __restrict__ statC,
                            short* __restrict__ CLb, int nl) {
    int idx = blockIdx.x * 256 + threadIdx.x;
    if (idx >= nl * 20) return;
    int r = idx / 20, q = idx % 20;
    int p0 = row_ptr[r], p1 = row_ptr[r + 1];
    float a0 = 0.f, a1 = 0.f, a2 = 0.f, a3 = 0.f;
    int p = p0;
    if (Cb) {
        const short4* Cb4 = (const short4*)Cb;
        for (; p + 2 <= p1; p += 2) {
            short4 v0 = Cb4[(size_t)cl_of[p] * 20 + q];
            short4 v1 = Cb4[(size_t)cl_of[p + 1] * 20 + q];
            a0 += bf2f(v0.x) + bf2f(v1.x);
            a1 += bf2f(v0.y) + bf2f(v1.y);
            a2 += bf2f(v0.z) + bf2f(v1.z);
            a3 += bf2f(v0.w) + bf2f(v1.w);
        }
        if (p < p1) {
            short4 v0 = Cb4[(size_t)cl_of[p] * 20 + q];
            a0 += bf2f(v0.x); a1 += bf2f(v0.y); a2 += bf2f(v0.z); a3 += bf2f(v0.w);
        }
    } else {
        const float4* C4 = (const float4*)C;
        for (; p + 2 <= p1; p += 2) {
            float4 v0 = C4[(size_t)cl_of[p] * 20 + q];
            float4 v1 = C4[(size_t)cl_of[p + 1] * 20 + q];
            a0 += v0.x + v1.x; a1 += v0.y + v1.y;
            a2 += v0.z + v1.z; a3 += v0.w + v1.w;
        }
        if (p < p1) {
            float4 v0 = C4[(size_t)cl_of[p] * 20 + q];
            a0 += v0.x; a1 += v0.y; a2 += v0.z; a3 += v0.w;
        }
    }
    float n = (float)(p1 - p0), s = *scp;
    int col = 4 * q;
    short4 o;
    o.x = f2bf((a0 - n * statC[col])     * statC[80 + col]     * s);
    o.y = f2bf((a1 - n * statC[col + 1]) * statC[80 + col + 1] * s);
    o.z = f2bf((a2 - n * statC[col + 2]) * statC[80 + col + 2] * s);
    o.w = f2bf((a3 - n * statC[col + 3]) * statC[80 + col + 3] * s);
    ((short4*)CLb)[idx] = o;
}

// ---------------- fused L update ----------------
// paired rows [vb,vb+32) u [vb+nv,vb+nv+32). If CLb: pure coalesced staging.
// Else: round-4 inline CSR gather fallback.
__launch_bounds__(256, 2)
__global__ void k_l_update(float* __restrict__ L, const short* __restrict__ Lb,
                           const float* __restrict__ C, const short* __restrict__ Cb,
                           const short* __restrict__ CLb,
                           const int* __restrict__ row_ptr, const int* __restrict__ cl_of,
                           const float* __restrict__ scp,
                           const short8* __restrict__ W0p, const float* __restrict__ b0,
                           const short8* __restrict__ W1p, const float* __restrict__ b1,
                           const float* __restrict__ statC, const float* __restrict__ statL,
                           float* __restrict__ accumL, int nv) {
    constexpr int SK = 264;
    __shared__ short lds[64 * SK];             // input K=256, then hidden 240+16pad
    __shared__ float sred[160], sC[160], sL[160];
    const int lane = threadIdx.x, wy = threadIdx.y, tid = wy * 64 + lane;
    const int vb = blockIdx.x * 32;

    if (tid < 160) { sred[tid] = 0.f; sC[tid] = statC[tid]; sL[tid] = statL[tid]; }
    __syncthreads();

    const float s = *scp;
    if (CLb) {
        // all-coalesced staging: seg0, seg1 (CLb), seg2, pad
        for (int it = tid; it < 64 * 64; it += 256) {
            int lr = it >> 6, q = it & 63;
            short* dst = lds + lr * SK;
            int r = (lr < 32) ? vb + lr : vb + nv + (lr - 32);
            if (q < 20) {
                int col = 4 * q;
                if (Lb) {
                    const short* p = Lb + ((lr < 32) ? (size_t)(vb + lr) * 160
                                                     : (size_t)(vb + lr - 32) * 160 + 80) + col;
                    *(short4*)(dst + col) = *(const short4*)p;
                } else {
                    float4 v = ((const float4*)L)[(size_t)r * 20 + q];
                    store_bf4(dst + col,
                              (v.x - sL[col]) * sL[80 + col],
                              (v.y - sL[col + 1]) * sL[80 + col + 1],
                              (v.z - sL[col + 2]) * sL[80 + col + 2],
                              (v.w - sL[col + 3]) * sL[80 + col + 3]);
                }
            } else if (q < 40) {
                int qq = q - 20;
                *(short4*)(dst + 80 + 4 * qq) = ((const short4*)CLb)[(size_t)r * 20 + qq];
            } else if (q < 60) {
                int qq = q - 40, col = 4 * qq;
                if (Lb) {
                    const short* p = Lb + ((lr < 32) ? (size_t)(vb + lr) * 160 + 80
                                                     : (size_t)(vb + lr - 32) * 160) + col;
                    *(short4*)(dst + 160 + col) = *(const short4*)p;
                } else {
                    int fr = (r < nv) ? r + nv : r - nv;
                    float4 v = ((const float4*)L)[(size_t)fr * 20 + qq];
                    store_bf4(dst + 160 + col,
                              (v.x - sL[col]) * sL[80 + col],
                              (v.y - sL[col + 1]) * sL[80 + col + 1],
                              (v.z - sL[col + 2]) * sL[80 + col + 2],
                              (v.w - sL[col + 3]) * sL[80 + col + 3]);
                }
            } else {
                short4 z; z.x = 0; z.y = 0; z.z = 0; z.w = 0;
                *(short4*)(dst + 240 + 4 * (q - 60)) = z;
            }
        }
    } else {
        // round-4 fallback: inline CSR gather at q in [20,40)
        for (int it = tid; it < 64 * 64; it += 256) {
            int lr = it >> 6, q = it & 63;
            short* dst = lds + lr * SK;
            int r = (lr < 32) ? vb + lr : vb + nv + (lr - 32);
            if (q < 20) {
                int col = 4 * q;
                if (Lb) {
                    const short* p = Lb + ((lr < 32) ? (size_t)(vb + lr) * 160
                                                     : (size_t)(vb + lr - 32) * 160 + 80) + col;
                    *(short4*)(dst + col) = *(const short4*)p;
                } else {
                    float4 v = ((const float4*)L)[(size_t)r * 20 + q];
                    store_bf4(dst + col,
                              (v.x - sL[col]) * sL[80 + col],
                              (v.y - sL[col + 1]) * sL[80 + col + 1],
                              (v.z - sL[col + 2]) * sL[80 + col + 2],
                              (v.w - sL[col + 3]) * sL[80 + col + 3]);
                }
            } else if (q < 40) {
                int qq = q - 20, col = 4 * qq;
                int p0 = row_ptr[r], p1 = row_ptr[r + 1];
                float ax = 0.f, ay = 0.f, az = 0.f, aw = 0.f;
                int p = p0;
                if (Cb) {
                    const short4* Cb4 = (const short4*)Cb;
                    for (; p + 2 <= p1; p += 2) {
                        short4 v0 = Cb4[(size_t)cl_of[p] * 20 + qq];
                        short4 v1 = Cb4[(size_t)cl_of[p + 1] * 20 + qq];
                        ax += bf2f(v0.x) + bf2f(v1.x);
                        ay += bf2f(v0.y) + bf2f(v1.y);
                        az += bf2f(v0.z) + bf2f(v1.z);
                        aw += bf2f(v0.w) + bf2f(v1.w);
                    }
                    if (p < p1) {
                        short4 v0 = Cb4[(size_t)cl_of[p] * 20 + qq];
                        ax += bf2f(v0.x); ay += bf2f(v0.y); az += bf2f(v0.z); aw += bf2f(v0.w);
                    }
                } else {
                    const float4* C4 = (const float4*)C;
                    for (; p < p1; ++p) {
                        float4 v = C4[(size_t)cl_of[p] * 20 + qq];
                        ax += v.x; ay += v.y; az += v.z; aw += v.w;
                    }
                }
                float n = (float)(p1 - p0);
                store_bf4(dst + 80 + col,
                          (ax - n * sC[col]) * sC[80 + col] * s,
                          (ay - n * sC[col + 1]) * sC[80 + col + 1] * s,
                          (az - n * sC[col + 2]) * sC[80 + col + 2] * s,
                          (aw - n * sC[col + 3]) * sC[80 + col + 3] * s);
            } else if (q < 60) {
                int qq = q - 40, col = 4 * qq;
                if (Lb) {
                    const short* p = Lb + ((lr < 32) ? (size_t)(vb + lr) * 160 + 80
                                                     : (size_t)(vb + lr - 32) * 160) + col;
                    *(short4*)(dst + 160 + col) = *(const short4*)p;
                } else {
                    int fr = (r < nv) ? r + nv : r - nv;
                    float4 v = ((const float4*)L)[(size_t)fr * 20 + qq];
                    store_bf4(dst + 160 + col,
                              (v.x - sL[col]) * sL[80 + col],
                              (v.y - sL[col + 1]) * sL[80 + col + 1],
                              (v.z - sL[col + 2]) * sL[80 + col + 2],
                              (v.w - sL[col + 3]) * sL[80 + col + 3]);
                }
            } else {
                short4 z; z.x = 0; z.y = 0; z.z = 0; z.w = 0;
                *(short4*)(dst + 240 + 4 * (q - 60)) = z;
            }
        }
    }
    __syncthreads();   // staging crosses stripes; rest is wave-private

    const int quad = lane >> 4, l15 = lane & 15, wr0 = wy * 16, arow = wr0 + l15;

    f32x4 acc[15];
#pragma unroll
    for (int nb = 0; nb < 15; ++nb) { f32x4 z = {0.f, 0.f, 0.f, 0.f}; acc[nb] = z; }
    mfma_layer<8, 15>(lds, SK, W0p, acc, lane, arow);
    write_hidden<15>(lds, SK, acc, b0, l15, quad, wr0);
    {   // zero-pad hidden cols 240..255 of OWN stripe (wave-private)
        int row = wr0 + (lane >> 2);
        int c = 240 + (lane & 3) * 4;
        short4 z; z.x = 0; z.y = 0; z.z = 0; z.w = 0;
        *(short4*)(lds + row * SK + c) = z;
    }

    f32x4 acc2[5];
#pragma unroll
    for (int nb = 0; nb < 5; ++nb) { f32x4 z = {0.f, 0.f, 0.f, 0.f}; acc2[nb] = z; }
    mfma_layer<8, 5>(lds, SK, W1p, acc2, lane, arow);

#pragma unroll
    for (int nb = 0; nb < 5; ++nb) {
        int cc = nb * 16 + l15;
        float bv = b1[cc];
        float s1 = 0.f, s2 = 0.f;
#pragma unroll
        for (int reg = 0; reg < 4; ++reg) {
            int lr = wr0 + quad * 4 + reg;
            int rabs = (lr < 32) ? vb + lr : vb + nv + (lr - 32);
            float v = acc2[nb][reg] + bv;
            L[(size_t)rabs * 80 + cc] = v;
            s1 += v; s2 += v * v;
        }
        s1 += __shfl_xor(s1, 16); s1 += __shfl_xor(s1, 32);
        s2 += __shfl_xor(s2, 16); s2 += __shfl_xor(s2, 32);
        if (quad == 0) { atomicAdd(&sred[cc], s1); atomicAdd(&sred[80 + cc], s2); }
    }
    __syncthreads();
    if (tid < 160) atomicAdd(&accumL[tid], sred[tid]);
}

// ---------------- stats finalize (separate dispatch, round-4 form) ----------------
__global__ void k_stats_final(float* __restrict__ accum, float* __restrict__ stat,
                              float Minv) {
    int i = threadIdx.x;          // 160 threads
    float own = accum[i];
    float hi  = (i < 80) ? accum[80 + i] : 0.f;
    __syncthreads();
    accum[i] = 0.f;
    if (i < 80) {
        float mean = own * Minv;
        float var  = hi * Minv - mean * mean;
        stat[i] = mean;
        stat[80 + i] = rsqrtf(var + NORM_EPS);
    }
}

// ---------------- fused V head (4 layers, single LDS buffer) ----------------
__launch_bounds__(256, 2)
__global__ void k_v_head(const float* __restrict__ L, const float* __restrict__ statL,
                         const short8* __restrict__ W0p, const float* __restrict__ b0,
                         const short8* __restrict__ W1p, const float* __restrict__ b1,
                         const short8* __restrict__ W2p, const float* __restrict__ b2,
                         const float* __restrict__ W3, const float* __restrict__ b3,
                         float* __restrict__ logits, short* __restrict__ Lb, int nv) {
    constexpr int SK = 168;
    __shared__ short lds[64 * SK];
    __shared__ float sW3[160], sL[160];
    const int lane = threadIdx.x, wy = threadIdx.y, tid = wy * 64 + lane;
    const int v0 = blockIdx.x * 64;
    const int cnt = (nv - v0 < 64) ? (nv - v0) : 64;

    if (tid < 160) { sW3[tid] = W3[tid]; sL[tid] = statL[tid]; }
    __syncthreads();

    for (int it = tid; it < 64 * 40; it += 256) {
        int lr = it / 40, q = it % 40;
        int v = v0 + ((lr < cnt) ? lr : cnt - 1);
        int qq = (q < 20) ? q : q - 20;
        int rr = (q < 20) ? v : v + nv;
        int col = 4 * q, scol = 4 * qq;
        float4 x = ((const float4*)L)[(size_t)rr * 20 + qq];
        short4 o;
        o.x = f2bf((x.x - sL[scol]) * sL[80 + scol]);
        o.y = f2bf((x.y - sL[scol + 1]) * sL[80 + scol + 1]);
        o.z = f2bf((x.z - sL[scol + 2]) * sL[80 + scol + 2]);
        o.w = f2bf((x.w - sL[scol + 3]) * sL[80 + scol + 3]);
        *(short4*)(lds + lr * SK + col) = o;
        if (Lb && lr < cnt) *(short4*)(Lb + (size_t)v * 160 + col) = o;
    }
    __syncthreads();   // staging crosses stripes

    const int quad = lane >> 4, l15 = lane & 15, wr0 = wy * 16, arow = wr0 + l15;

    f32x4 acc[10];
#pragma unroll
    for (int nb = 0; nb < 10; ++nb) { f32x4 z = {0.f, 0.f, 0.f, 0.f}; acc[nb] = z; }
    mfma_layer<5, 10>(lds, SK, W0p, acc, lane, arow);
    write_hidden<10>(lds, SK, acc, b0, l15, quad, wr0);

#pragma unroll
    for (int nb = 0; nb < 10; ++nb) { f32x4 z = {0.f, 0.f, 0.f, 0.f}; acc[nb] = z; }
    mfma_layer<5, 10>(lds, SK, W1p, acc, lane, arow);
    write_hidden<10>(lds, SK, acc, b1, l15, quad, wr0);

#pragma unroll
    for (int nb = 0; nb < 10; ++nb) { f32x4 z = {0.f, 0.f, 0.f, 0.f}; acc[nb] = z; }
    mfma_layer<5, 10>(lds, SK, W2p, acc, lane, arow);
    write_hidden<10>(lds, SK, acc, b2, l15, quad, wr0);
    __syncthreads();   // final dot reads across stripes

    int lrow = tid >> 2, t4 = tid & 3;
    float v = 0.f;
    for (int c = t4; c < 160; c += 4) v += bf2f(lds[lrow * SK + c]) * sW3[c];
    v += __shfl_down(v, 2, 4);
    v += __shfl_down(v, 1, 4);
    if (t4 == 0 && lrow < cnt) logits[v0 + lrow] = v + b3[0];
}

// ---------------- loss ----------------
__device__ __forceinline__ float softplusf(float x) {
    return fmaxf(x, 0.f) + log1pf(expf(-fabsf(x)));
}

__global__ void k_loss(const float* __restrict__ logits, const int* __restrict__ lit_var,
                       const int* __restrict__ lit_neg, float* __restrict__ loss_acc,
                       int cpg) {
    const int g = blockIdx.x;
    const int tid = threadIdx.x;
    float part = 0.f;
    int cend = (g + 1) * cpg;
    for (int c = g * cpg + tid; c < cend; c += 256) {
        float cs = 0.f;
#pragma unroll
        for (int t = 0; t < 3; ++t) {
            int i = c * 3 + t;
            float sign = lit_neg[i] ? -1.f : 1.f;
            cs += softplusf(logits[lit_var[i]] * sign);
        }
        float vc = expf(-cs);
        part += vc * (-log1pf(LOSS_EPS - vc));
    }
    __shared__ float red[256];
    red[tid] = part;
    __syncthreads();
    for (int s = 128; s > 0; s >>= 1) {
        if (tid < s) red[tid] += red[tid + s];
        __syncthreads();
    }
    if (tid == 0) atomicAdd(loss_acc, sqrtf(red[0] + 1e-6f));
}

__global__ void k_output(float* __restrict__ dout, const float* __restrict__ logits,
                         const float* __restrict__ loss_acc, int nv) {
    int i = blockIdx.x * 256 + threadIdx.x;
    if (i < nv) dout[i] = logits[i];
    else if (i == nv) dout[i] = loss_acc[0] * (1.f / (float)NROUNDS);
}

// ---------------- host ----------------

extern "C" void kernel_launch(void* const* d_in, const int* in_sizes, int n_in,
                              void* d_out, int out_size, void* d_ws, size_t ws_size,
                              hipStream_t stream) {
    const int* lit_var    = (const int*)d_in[0];
    const int* lit_neg    = (const int*)d_in[1];
    const int* clause_idx = (const int*)d_in[2];
    const float* Lscale = (const float*)d_in[7];
    const float* Cscale = (const float*)d_in[8];
    const float* LCs    = (const float*)d_in[9];
    const float* CLs    = (const float*)d_in[10];
    const float* LuW0 = (const float*)d_in[11]; const float* Lub0 = (const float*)d_in[12];
    const float* LuW1 = (const float*)d_in[13]; const float* Lub1 = (const float*)d_in[14];
    const float* CuW0 = (const float*)d_in[15]; const float* Cub0 = (const float*)d_in[16];
    const float* CuW1 = (const float*)d_in[17]; const float* Cub1 = (const float*)d_in[18];
    const float* VsW0 = (const float*)d_in[19]; const float* Vsb0 = (const float*)d_in[20];
    const float* VsW1 = (const float*)d_in[21]; const float* Vsb1 = (const float*)d_in[22];
    const float* VsW2 = (const float*)d_in[23]; const float* Vsb2 = (const float*)d_in[24];
    const float* VsW3 = (const float*)d_in[25]; const float* Vsb3 = (const float*)d_in[26];

    const int ncell = in_sizes[0];          // 1,260,000
    const int ncl   = in_sizes[3];          // 420,000
    const int nv    = NV_CONST;
    const int nl    = 2 * nv;
    const int ng    = NG_CONST;

    size_t off = 0;
    auto A = [&](size_t bytes) -> void* {
        void* q = (char*)d_ws + off;
        off = (off + bytes + 255) & ~(size_t)255;
        return q;
    };
    float* L      = (float*)A((size_t)nl  * 80 * 4);   // raw L state
    float* C      = (float*)A((size_t)ncl * 80 * 4);   // raw C state
    float* logits = (float*)A((size_t)nv * 4);
    float* statC  = (float*)A(160 * 4);
    float* statL  = (float*)A(160 * 4);
    float* accumC = (float*)A(160 * 4);
    float* accumL = (float*)A(160 * 4);
    float* loss_a = (float*)A(256);
    int* litrow  = (int*)A((size_t)ncell * 4);
    int* row_ptr = (int*)A((size_t)(nl + 1) * 4);
    int* tmp     = (int*)A((size_t)nl * 4);
    int* cl_of   = (int*)A((size_t)ncell * 4);
    short* CuW0p = (short*)A((size_t)10 * 5 * 64 * 16);
    short* CuW1p = (short*)A((size_t)5  * 5 * 64 * 16);
    short* LuW0p = (short*)A((size_t)15 * 8 * 64 * 16);
    short* LuW1p = (short*)A((size_t)5  * 8 * 64 * 16);
    short* VsW0p = (short*)A((size_t)10 * 5 * 64 * 16);
    short* VsW1p = (short*)A((size_t)10 * 5 * 64 * 16);
    short* VsW2p = (short*)A((size_t)10 * 5 * 64 * 16);
    // optional buffers, priority: CLb (gather split) > Cb (gather BW) > Lb
    size_t clb_bytes = (size_t)nl * 80 * 2;
    short* CLb = nullptr;
    if (off + clb_bytes + 256 <= ws_size) CLb = (short*)A(clb_bytes);
    size_t cb_bytes = (size_t)ncl * 80 * 2;
    short* Cb = nullptr;
    if (off + cb_bytes + 256 <= ws_size) Cb = (short*)A(cb_bytes);
    size_t lb_bytes = (size_t)nv * 160 * 2;
    short* Lb = nullptr;
    if (off + lb_bytes + 256 <= ws_size) Lb = (short*)A(lb_bytes);

    const dim3 B64x4(64, 4, 1);

    // ---- setup ----
    k_zero_i<<<(nl + 255) / 256, 256, 0, stream>>>(tmp, nl);
    k_init_stats<<<1, 192, 0, stream>>>(statC, statL, accumC, accumL, loss_a);
    k_litrow<<<(ncell + 255) / 256, 256, 0, stream>>>(lit_var, lit_neg, litrow, tmp, ncell, nv);
    k_scan4<<<1, 1024, 0, stream>>>(tmp, row_ptr, nl, ncell);
    k_copy_int<<<(nl + 255) / 256, 256, 0, stream>>>(tmp, row_ptr, nl);
    k_fill_csr<<<(ncell + 255) / 256, 256, 0, stream>>>(litrow, clause_idx, tmp, cl_of, ncell);
    k_fill<<<(nl * 80 + 255) / 256, 256, 0, stream>>>(L, nl * 80, Lscale);
    k_fill<<<(ncl * 80 + 255) / 256, 256, 0, stream>>>(C, ncl * 80, Cscale);
    if (Lb) k_fill_b<<<(nv * 160 + 255) / 256, 256, 0, stream>>>(Lb, nv * 160, Lscale);
    if (Cb) k_fill_b<<<(ncl * 80 + 255) / 256, 256, 0, stream>>>(Cb, ncl * 80, Cscale);
    k_pack_w<<<(10 * 5 * 64 + 255) / 256, 256, 0, stream>>>(CuW0, CuW0p, 160, 160, 5, 10);
    k_pack_w<<<(5  * 5 * 64 + 255) / 256, 256, 0, stream>>>(CuW1, CuW1p, 160, 80, 5, 5);
    k_pack_w<<<(15 * 8 * 64 + 255) / 256, 256, 0, stream>>>(LuW0, LuW0p, 240, 240, 8, 15);
    k_pack_w<<<(5  * 8 * 64 + 255) / 256, 256, 0, stream>>>(LuW1, LuW1p, 240, 80, 8, 5);
    k_pack_w<<<(10 * 5 * 64 + 255) / 256, 256, 0, stream>>>(VsW0, VsW0p, 160, 160, 5, 10);
    k_pack_w<<<(10 * 5 * 64 + 255) / 256, 256, 0, stream>>>(VsW1, VsW1p, 160, 160, 5, 10);
    k_pack_w<<<(10 * 5 * 64 + 255) / 256, 256, 0, stream>>>(VsW2, VsW2p, 160, 160, 5, 10);

    const int cblk = (ncl + 63) / 64;       // 6563
    const int lblk = nv / 32;               // 3125
    const int vblk = (nv + 63) / 64;        // 1563
    const int gblk = (nl * 20 + 255) / 256; // 15625

    for (int r = 0; r < NROUNDS; ++r) {
        k_c_update<<<cblk, B64x4, 0, stream>>>(
            C, Cb, L, Lb, litrow, LCs, (const short8*)CuW0p, Cub0, (const short8*)CuW1p, Cub1,
            statC, statL, accumC, ncl, nv);
        k_stats_final<<<1, 160, 0, stream>>>(accumC, statC, 1.f / (float)ncl);
        if (CLb)
            k_cl_gather<<<gblk, 256, 0, stream>>>(C, Cb, row_ptr, cl_of, CLs, statC, CLb, nl);
        k_l_update<<<lblk, B64x4, 0, stream>>>(
            L, Lb, C, Cb, CLb, row_ptr, cl_of, CLs, (const short8*)LuW0p, Lub0,
            (const short8*)LuW1p, Lub1, statC, statL, accumL, nv);
        k_stats_final<<<1, 160, 0, stream>>>(accumL, statL, 1.f / (float)nl);
        k_v_head<<<vblk, B64x4, 0, stream>>>(
            L, statL, (const short8*)VsW0p, Vsb0, (const short8*)VsW1p, Vsb1,
            (const short8*)VsW2p, Vsb2, VsW3, Vsb3, logits, Lb, nv);
        k_loss<<<ng, 256, 0, stream>>>(logits, lit_var, lit_neg, loss_a, ncl / ng);
    }

    k_output<<<(nv + 1 + 255) / 256, 256, 0, stream>>>((float*)d_out, logits, loss_a, nv);
}

// Round 8
// 16330.360 us; speedup vs baseline: 3.6380x; 1.2012x over previous
//
#include <hip/hip_runtime.h>
#include <math.h>

// SimpleNeuroSAT on MI355X — round 7: bf16-only state (hot set ~163MB < L3),
// round-indexed stat slabs (no 1-block stats dispatches), short8 staging.
// Structure relied on: clause c owns cells 3c..3c+2, graphs contiguous, n_vars=100000.
// MFMA 16x16x32_bf16: A[m=lane&15][k=quad*8+j]; B[k=quad*8+j][n=lane&15];
// D: col=lane&15, row=quad*4+reg (HW-verified m89/m91/m120).
// State: Cb raw bf16 C; Lraw raw bf16 L; Lb pre-normed bf16 L [v|v+nv]; CLb bf16 msgs.
// Stats: slabC/slabL[33][160] accumulated once per round, consumers finalize inline.

#define NROUNDS 32
#define NORM_EPS 1e-3f
#define LOSS_EPS 1e-8f

static constexpr int NV_CONST = 100000;
static constexpr int NG_CONST = 100;

typedef __attribute__((ext_vector_type(8))) short short8;
typedef __attribute__((ext_vector_type(4))) float f32x4;

__device__ __forceinline__ short f2bf(float f) {
    union { float f; unsigned u; } x; x.f = f;
    unsigned r = x.u + 0x7fffu + ((x.u >> 16) & 1u);   // RNE
    return (short)(r >> 16);
}
__device__ __forceinline__ float bf2f(short s) {
    union { unsigned u; float f; } x; x.u = ((unsigned)(unsigned short)s) << 16;
    return x.f;
}

// ---------------- setup kernels ----------------

__global__ void k_zero_i(int* __restrict__ p, int n) {
    int i = blockIdx.x * 256 + threadIdx.x;
    if (i < n) p[i] = 0;
}
__global__ void k_fill_b(short* __restrict__ p, int n, const float* __restrict__ vp) {
    int i = blockIdx.x * 256 + threadIdx.x;
    if (i < n) p[i] = f2bf(*vp);
}
__global__ void k_copy_int(int* __restrict__ dst, const int* __restrict__ src, int n) {
    int i = blockIdx.x * 256 + threadIdx.x;
    if (i < n) dst[i] = src[i];
}
// zero all slabs; slabC[0] = identity (mean 0, E[x^2]=ncl*(1-eps) so rstd==1 exactly)
__global__ void k_init_slabs(float* __restrict__ slabC, float* __restrict__ slabL,
                             float* __restrict__ loss_a, float nclf) {
    int i = blockIdx.x * 256 + threadIdx.x;
    if (i < 33 * 160) {
        slabC[i] = (i >= 80 && i < 160) ? nclf * (1.f - NORM_EPS) : 0.f;
        slabL[i] = 0.f;
    }
    if (i == 0) loss_a[0] = 0.f;
}

__global__ void k_litrow(const int* __restrict__ lit_var, const int* __restrict__ lit_neg,
                         int* __restrict__ litrow, int* __restrict__ counts,
                         int ncell, int nv) {
    int i = blockIdx.x * 256 + threadIdx.x;
    if (i < ncell) {
        int r = lit_var[i] + lit_neg[i] * nv;
        litrow[i] = r;
        atomicAdd(&counts[r], 1);
    }
}

__launch_bounds__(1024)
__global__ void k_scan4(const int* __restrict__ counts, int* __restrict__ row_ptr,
                        int n, int total) {
    __shared__ int sd[1024];
    __shared__ int carry;
    int tid = threadIdx.x;
    if (tid == 0) carry = 0;
    __syncthreads();
    for (int base = 0; base < n; base += 4096) {
        int i0 = base + tid * 4;
        int a0 = (i0 + 0 < n) ? counts[i0 + 0] : 0;
        int a1 = (i0 + 1 < n) ? counts[i0 + 1] : 0;
        int a2 = (i0 + 2 < n) ? counts[i0 + 2] : 0;
        int a3 = (i0 + 3 < n) ? counts[i0 + 3] : 0;
        int s = a0 + a1 + a2 + a3;
        sd[tid] = s;
        __syncthreads();
        for (int off = 1; off < 1024; off <<= 1) {
            int t = (tid >= off) ? sd[tid - off] : 0;
            __syncthreads();
            sd[tid] += t;
            __syncthreads();
        }
        int excl = carry + sd[tid] - s;
        if (i0 + 0 < n) row_ptr[i0 + 0] = excl;
        if (i0 + 1 < n) row_ptr[i0 + 1] = excl + a0;
        if (i0 + 2 < n) row_ptr[i0 + 2] = excl + a0 + a1;
        if (i0 + 3 < n) row_ptr[i0 + 3] = excl + a0 + a1 + a2;
        __syncthreads();
        if (tid == 0) carry += sd[1023];
        __syncthreads();
    }
    if (tid == 0) row_ptr[n] = total;
}

__global__ void k_fill_csr(const int* __restrict__ litrow, const int* __restrict__ clause_idx,
                           int* __restrict__ cursor, int* __restrict__ cl_of, int ncell) {
    int i = blockIdx.x * 256 + threadIdx.x;
    if (i < ncell) {
        int r = litrow[i];
        int pos = atomicAdd(&cursor[r], 1);
        cl_of[pos] = clause_idx[i];
    }
}

// Wp frag t=(nb*KB+kb)*64+lane holds W[kb*32+quad*8+j][nb*16+(lane&15)], zero-padded.
__global__ void k_pack_w(const float* __restrict__ W, short* __restrict__ Wp,
                         int K, int N, int KB, int NB) {
    int t = blockIdx.x * 256 + threadIdx.x;
    int tot = NB * KB * 64;
    if (t >= tot) return;
    int lane = t & 63;
    int kb = (t >> 6) % KB;
    int nb = t / (64 * KB);
    int quad = lane >> 4, l15 = lane & 15;
    int n = nb * 16 + l15;
#pragma unroll
    for (int j = 0; j < 8; ++j) {
        int k = kb * 32 + quad * 8 + j;
        float f = (k < K && n < N) ? W[(size_t)k * N + n] : 0.f;
        Wp[(size_t)t * 8 + j] = f2bf(f);
    }
}

// ---------------- MFMA building blocks ----------------

template <int KB, int NB>
__device__ __forceinline__ void mfma_layer(const short* lds, int SK,
                                           const short8* __restrict__ Wp,
                                           f32x4* acc, int lane, int arow) {
    const int quad8 = (lane >> 4) * 8;
    short8 a[KB];
#pragma unroll
    for (int kb = 0; kb < KB; ++kb)
        a[kb] = *(const short8*)(lds + arow * SK + kb * 32 + quad8);
#pragma unroll
    for (int kb = 0; kb < KB; ++kb)
#pragma unroll
        for (int nb = 0; nb < NB; ++nb)
            acc[nb] = __builtin_amdgcn_mfma_f32_16x16x32_bf16(
                a[kb], Wp[(nb * KB + kb) * 64 + lane], acc[nb], 0, 0, 0);
}

// wave-private: writes only rows wr0..wr0+15 (same stripe the wave reads)
template <int NB>
__device__ __forceinline__ void write_hidden(short* ldsH, int SKH, const f32x4* acc,
                                             const float* __restrict__ bias,
                                             int l15, int quad, int wr0) {
#pragma unroll
    for (int nb = 0; nb < NB; ++nb) {
        int c = nb * 16 + l15;
        float bv = bias[c];
#pragma unroll
        for (int reg = 0; reg < 4; ++reg) {
            int row = wr0 + quad * 4 + reg;
            float v = acc[nb][reg] + bv;
            v = fminf(fmaxf(v, 0.f), 6.f);
            ldsH[row * SKH + c] = f2bf(v);
        }
    }
}

// compute mean/rstd from an accum slab into shared sS[160] (callers sync after)
__device__ __forceinline__ void load_stats(const float* __restrict__ slab, float Minv,
                                           float* sS, int tid) {
    if (tid < 80) {
        float m = slab[tid] * Minv;
        float v = slab[80 + tid] * Minv - m * m;
        sS[tid] = m;
        sS[80 + tid] = rsqrtf(v + NORM_EPS);
    }
}

// ---------------- fused C update (bf16 state) ----------------
__launch_bounds__(256, 2)
__global__ void k_c_update(short* __restrict__ Cb, const short* __restrict__ Lb,
                           const int* __restrict__ litrow, const float* __restrict__ scp,
                           const short8* __restrict__ W0p, const float* __restrict__ b0,
                           const short8* __restrict__ W1p, const float* __restrict__ b1,
                           const float* __restrict__ prevSlab, float* __restrict__ nextSlab,
                           float Minv, int ncl, int nv) {
    constexpr int SK = 168;
    __shared__ short lds[64 * SK];
    __shared__ float sred[160], sC[160];
    const int lane = threadIdx.x, wy = threadIdx.y, tid = wy * 64 + lane;
    const int r0 = blockIdx.x * 64;
    const int rows = (ncl - r0 < 64) ? (ncl - r0) : 64;

    if (tid < 160) sred[tid] = 0.f;
    load_stats(prevSlab, Minv, sC, tid);
    __syncthreads();

    const float s = *scp;
    const short8* Cb8 = (const short8*)Cb;
    const short8* Lb8 = (const short8*)Lb;
    for (int it = tid; it < 64 * 20; it += 256) {
        int lr = it / 20, c = it % 20;
        int cl = r0 + ((lr < rows) ? lr : rows - 1);
        if (c < 10) {
            short8 v = Cb8[(size_t)cl * 10 + c];
            int col = c * 8;
            short8 o;
#pragma unroll
            for (int j = 0; j < 8; ++j)
                o[j] = f2bf((bf2f(v[j]) - sC[col + j]) * sC[80 + col + j]);
            *(short8*)(lds + lr * SK + col) = o;
        } else {
            int cc = c - 10, b = cl * 3;
            int ra = litrow[b], rb = litrow[b + 1], rc = litrow[b + 2];
            short8 va = Lb8[(ra < nv) ? (size_t)ra * 20 + cc : (size_t)(ra - nv) * 20 + 10 + cc];
            short8 vb = Lb8[(rb < nv) ? (size_t)rb * 20 + cc : (size_t)(rb - nv) * 20 + 10 + cc];
            short8 vc = Lb8[(rc < nv) ? (size_t)rc * 20 + cc : (size_t)(rc - nv) * 20 + 10 + cc];
            short8 o;
#pragma unroll
            for (int j = 0; j < 8; ++j)
                o[j] = f2bf((bf2f(va[j]) + bf2f(vb[j]) + bf2f(vc[j])) * s);
            *(short8*)(lds + lr * SK + 80 + cc * 8) = o;
        }
    }
    __syncthreads();   // staging crosses stripes; everything after is wave-private

    const int quad = lane >> 4, l15 = lane & 15, wr0 = wy * 16, arow = wr0 + l15;

    f32x4 acc[10];
#pragma unroll
    for (int nb = 0; nb < 10; ++nb) { f32x4 z = {0.f, 0.f, 0.f, 0.f}; acc[nb] = z; }
    mfma_layer<5, 10>(lds, SK, W0p, acc, lane, arow);
    write_hidden<10>(lds, SK, acc, b0, l15, quad, wr0);

    f32x4 acc2[5];
#pragma unroll
    for (int nb = 0; nb < 5; ++nb) { f32x4 z = {0.f, 0.f, 0.f, 0.f}; acc2[nb] = z; }
    mfma_layer<5, 5>(lds, SK, W1p, acc2, lane, arow);

#pragma unroll
    for (int nb = 0; nb < 5; ++nb) {
        int cc = nb * 16 + l15;
        float bv = b1[cc];
        float s1 = 0.f, s2 = 0.f;
#pragma unroll
        for (int reg = 0; reg < 4; ++reg) {
            int lr = wr0 + quad * 4 + reg;
            if (lr < rows) {
                float v = acc2[nb][reg] + bv;
                Cb[(size_t)(r0 + lr) * 80 + cc] = f2bf(v);
                s1 += v; s2 += v * v;
            }
        }
        s1 += __shfl_xor(s1, 16); s1 += __shfl_xor(s1, 32);
        s2 += __shfl_xor(s2, 16); s2 += __shfl_xor(s2, 32);
        if (quad == 0) { atomicAdd(&sred[cc], s1); atomicAdd(&sred[80 + cc], s2); }
    }
    __syncthreads();
    if (tid < 160) atomicAdd(&nextSlab[tid], sred[tid]);
}

// ---------------- standalone CL gather (high-TLP, coalesced) ----------------
// thread = (row r, 8B chunk q of 20); 20 chunk-threads read each clause row as
// one contiguous 160B line. Writes CLb = normalized bf16 message.
__global__ void k_cl_gather(const short* __restrict__ Cb, const int* __restrict__ row_ptr,
                            const int* __restrict__ cl_of, const float* __restrict__ scp,
                            const float* __restrict__ slab, float Minv,
                            short* __restrict__ CLb, int nl) {
    __shared__ float sC[160];
    load_stats(slab, Minv, sC, threadIdx.x);
    __syncthreads();
    int idx = blockIdx.x * 256 + threadIdx.x;
    if (idx >= nl * 20) return;
    int r = idx / 20, q = idx % 20;
    int p0 = row_ptr[r], p1 = row_ptr[r + 1];
    float a0 = 0.f, a1 = 0.f, a2 = 0.f, a3 = 0.f;
    const short4* Cb4 = (const short4*)Cb;
    int p = p0;
    for (; p + 2 <= p1; p += 2) {
        short4 v0 = Cb4[(size_t)cl_of[p] * 20 + q];
        short4 v1 = Cb4[(size_t)cl_of[p + 1] * 20 + q];
        a0 += bf2f(v0.x) + bf2f(v1.x);
        a1 += bf2f(v0.y) + bf2f(v1.y);
        a2 += bf2f(v0.z) + bf2f(v1.z);
        a3 += bf2f(v0.w) + bf2f(v1.w);
    }
    if (p < p1) {
        short4 v0 = Cb4[(size_t)cl_of[p] * 20 + q];
        a0 += bf2f(v0.x); a1 += bf2f(v0.y); a2 += bf2f(v0.z); a3 += bf2f(v0.w);
    }
    float n = (float)(p1 - p0), s = *scp;
    int col = 4 * q;
    short4 o;
    o.x = f2bf((a0 - n * sC[col])     * sC[80 + col]     * s);
    o.y = f2bf((a1 - n * sC[col + 1]) * sC[80 + col + 1] * s);
    o.z = f2bf((a2 - n * sC[col + 2]) * sC[80 + col + 2] * s);
    o.w = f2bf((a3 - n * sC[col + 3]) * sC[80 + col + 3] * s);
    ((short4*)CLb)[idx] = o;
}

// ---------------- fused L update (pure coalesced staging) ----------------
// paired rows [vb,vb+32) u [vb+nv,vb+nv+32); writes Lraw bf16 + accumL slab.
__launch_bounds__(256, 2)
__global__ void k_l_update(short* __restrict__ Lraw, const short* __restrict__ Lb,
                           const short* __restrict__ CLb,
                           const short8* __restrict__ W0p, const float* __restrict__ b0,
                           const short8* __restrict__ W1p, const float* __restrict__ b1,
                           float* __restrict__ nextSlab, int nv) {
    constexpr int SK = 264;
    __shared__ short lds[64 * SK];             // input K=256, then hidden 240+16pad
    __shared__ float sred[160];
    const int lane = threadIdx.x, wy = threadIdx.y, tid = wy * 64 + lane;
    const int vb = blockIdx.x * 32;

    if (tid < 160) sred[tid] = 0.f;
    __syncthreads();

    const short8* Lb8  = (const short8*)Lb;
    const short8* CLb8 = (const short8*)CLb;
    for (int it = tid; it < 64 * 32; it += 256) {
        int lr = it >> 5, c = it & 31;
        short* dst = lds + lr * SK;
        int v = (lr < 32) ? vb + lr : vb + (lr - 32);
        int half0 = (lr < 32) ? 0 : 10;        // chunk offset of "own" half in Lb row
        if (c < 10) {
            *(short8*)(dst + c * 8) = Lb8[(size_t)v * 20 + half0 + c];
        } else if (c < 20) {
            int r = (lr < 32) ? vb + lr : vb + nv + (lr - 32);
            *(short8*)(dst + 80 + (c - 10) * 8) = CLb8[(size_t)r * 10 + (c - 10)];
        } else if (c < 30) {
            *(short8*)(dst + 160 + (c - 20) * 8) = Lb8[(size_t)v * 20 + (10 - half0) + (c - 20)];
        } else {
            short8 z = {0, 0, 0, 0, 0, 0, 0, 0};
            *(short8*)(dst + 240 + (c - 30) * 8) = z;
        }
    }
    __syncthreads();   // staging crosses stripes; rest is wave-private

    const int quad = lane >> 4, l15 = lane & 15, wr0 = wy * 16, arow = wr0 + l15;

    f32x4 acc[15];
#pragma unroll
    for (int nb = 0; nb < 15; ++nb) { f32x4 z = {0.f, 0.f, 0.f, 0.f}; acc[nb] = z; }
    mfma_layer<8, 15>(lds, SK, W0p, acc, lane, arow);
    write_hidden<15>(lds, SK, acc, b0, l15, quad, wr0);
    {   // zero-pad hidden cols 240..255 of OWN stripe (wave-private)
        int row = wr0 + (lane >> 2);
        int c = 240 + (lane & 3) * 4;
        short4 z; z.x = 0; z.y = 0; z.z = 0; z.w = 0;
        *(short4*)(lds + row * SK + c) = z;
    }

    f32x4 acc2[5];
#pragma unroll
    for (int nb = 0; nb < 5; ++nb) { f32x4 z = {0.f, 0.f, 0.f, 0.f}; acc2[nb] = z; }
    mfma_layer<8, 5>(lds, SK, W1p, acc2, lane, arow);

#pragma unroll
    for (int nb = 0; nb < 5; ++nb) {
        int cc = nb * 16 + l15;
        float bv = b1[cc];
        float s1 = 0.f, s2 = 0.f;
#pragma unroll
        for (int reg = 0; reg < 4; ++reg) {
            int lr = wr0 + quad * 4 + reg;
            int rabs = (lr < 32) ? vb + lr : vb + nv + (lr - 32);
            float v = acc2[nb][reg] + bv;
            Lraw[(size_t)rabs * 80 + cc] = f2bf(v);
            s1 += v; s2 += v * v;
        }
        s1 += __shfl_xor(s1, 16); s1 += __shfl_xor(s1, 32);
        s2 += __shfl_xor(s2, 16); s2 += __shfl_xor(s2, 32);
        if (quad == 0) { atomicAdd(&sred[cc], s1); atomicAdd(&sred[80 + cc], s2); }
    }
    __syncthreads();
    if (tid < 160) atomicAdd(&nextSlab[tid], sred[tid]);
}

// ---------------- fused V head (4 layers; also emits Lb) ----------------
__launch_bounds__(256, 2)
__global__ void k_v_head(const short* __restrict__ Lraw, const float* __restrict__ slab,
                         float Minv,
                         const short8* __restrict__ W0p, const float* __restrict__ b0,
                         const short8* __restrict__ W1p, const float* __restrict__ b1,
                         const short8* __restrict__ W2p, const float* __restrict__ b2,
                         const float* __restrict__ W3, const float* __restrict__ b3,
                         float* __restrict__ logits, short* __restrict__ Lb, int nv) {
    constexpr int SK = 168;
    __shared__ short lds[64 * SK];
    __shared__ float sW3[160], sL[160];
    const int lane = threadIdx.x, wy = threadIdx.y, tid = wy * 64 + lane;
    const int v0 = blockIdx.x * 64;
    const int cnt = (nv - v0 < 64) ? (nv - v0) : 64;

    if (tid < 160) sW3[tid] = W3[tid];
    load_stats(slab, Minv, sL, tid);
    __syncthreads();

    const short8* Lraw8 = (const short8*)Lraw;
    for (int it = tid; it < 64 * 20; it += 256) {
        int lr = it / 20, c = it % 20;
        int v = v0 + ((lr < cnt) ? lr : cnt - 1);
        int row = (c < 10) ? v : v + nv;
        int cc = (c < 10) ? c : c - 10;
        int col = cc * 8;
        short8 x = Lraw8[(size_t)row * 10 + cc];
        short8 o;
#pragma unroll
        for (int j = 0; j < 8; ++j)
            o[j] = f2bf((bf2f(x[j]) - sL[col + j]) * sL[80 + col + j]);
        *(short8*)(lds + lr * SK + c * 8) = o;
        if (lr < cnt) *(short8*)(Lb + (size_t)v * 160 + c * 8) = o;
    }
    __syncthreads();   // staging crosses stripes

    const int quad = lane >> 4, l15 = lane & 15, wr0 = wy * 16, arow = wr0 + l15;

    f32x4 acc[10];
#pragma unroll
    for (int nb = 0; nb < 10; ++nb) { f32x4 z = {0.f, 0.f, 0.f, 0.f}; acc[nb] = z; }
    mfma_layer<5, 10>(lds, SK, W0p, acc, lane, arow);
    write_hidden<10>(lds, SK, acc, b0, l15, quad, wr0);

#pragma unroll
    for (int nb = 0; nb < 10; ++nb) { f32x4 z = {0.f, 0.f, 0.f, 0.f}; acc[nb] = z; }
    mfma_layer<5, 10>(lds, SK, W1p, acc, lane, arow);
    write_hidden<10>(lds, SK, acc, b1, l15, quad, wr0);

#pragma unroll
    for (int nb = 0; nb < 10; ++nb) { f32x4 z = {0.f, 0.f, 0.f, 0.f}; acc[nb] = z; }
    mfma_layer<5, 10>(lds, SK, W2p, acc, lane, arow);
    write_hidden<10>(lds, SK, acc, b2, l15, quad, wr0);
    __syncthreads();   // final dot reads across stripes

    int lrow = tid >> 2, t4 = tid & 3;
    float v = 0.f;
    for (int c = t4; c < 160; c += 4) v += bf2f(lds[lrow * SK + c]) * sW3[c];
    v += __shfl_down(v, 2, 4);
    v += __shfl_down(v, 1, 4);
    if (t4 == 0 && lrow < cnt) logits[v0 + lrow] = v + b3[0];
}

// ---------------- loss ----------------
__device__ __forceinline__ float softplusf(float x) {
    return fmaxf(x, 0.f) + log1pf(expf(-fabsf(x)));
}

__global__ void k_loss(const float* __restrict__ logits, const int* __restrict__ lit_var,
                       const int* __restrict__ lit_neg, float* __restrict__ loss_acc,
                       int cpg) {
    const int g = blockIdx.x;
    const int tid = threadIdx.x;
    float part = 0.f;
    int cend = (g + 1) * cpg;
    for (int c = g * cpg + tid; c < cend; c += 256) {
        float cs = 0.f;
#pragma unroll
        for (int t = 0; t < 3; ++t) {
            int i = c * 3 + t;
            float sign = lit_neg[i] ? -1.f : 1.f;
            cs += softplusf(logits[lit_var[i]] * sign);
        }
        float vc = expf(-cs);
        part += vc * (-log1pf(LOSS_EPS - vc));
    }
    __shared__ float red[256];
    red[tid] = part;
    __syncthreads();
    for (int s = 128; s > 0; s >>= 1) {
        if (tid < s) red[tid] += red[tid + s];
        __syncthreads();
    }
    if (tid == 0) atomicAdd(loss_acc, sqrtf(red[0] + 1e-6f));
}

__global__ void k_output(float* __restrict__ dout, const float* __restrict__ logits,
                         const float* __restrict__ loss_acc, int nv) {
    int i = blockIdx.x * 256 + threadIdx.x;
    if (i < nv) dout[i] = logits[i];
    else if (i == nv) dout[i] = loss_acc[0] * (1.f / (float)NROUNDS);
}

// ---------------- host ----------------

extern "C" void kernel_launch(void* const* d_in, const int* in_sizes, int n_in,
                              void* d_out, int out_size, void* d_ws, size_t ws_size,
                              hipStream_t stream) {
    const int* lit_var    = (const int*)d_in[0];
    const int* lit_neg    = (const int*)d_in[1];
    const int* clause_idx = (const int*)d_in[2];
    const float* Lscale = (const float*)d_in[7];
    const float* Cscale = (const float*)d_in[8];
    const float* LCs    = (const float*)d_in[9];
    const float* CLs    = (const float*)d_in[10];
    const float* LuW0 = (const float*)d_in[11]; const float* Lub0 = (const float*)d_in[12];
    const float* LuW1 = (const float*)d_in[13]; const float* Lub1 = (const float*)d_in[14];
    const float* CuW0 = (const float*)d_in[15]; const float* Cub0 = (const float*)d_in[16];
    const float* CuW1 = (const float*)d_in[17]; const float* Cub1 = (const float*)d_in[18];
    const float* VsW0 = (const float*)d_in[19]; const float* Vsb0 = (const float*)d_in[20];
    const float* VsW1 = (const float*)d_in[21]; const float* Vsb1 = (const float*)d_in[22];
    const float* VsW2 = (const float*)d_in[23]; const float* Vsb2 = (const float*)d_in[24];
    const float* VsW3 = (const float*)d_in[25]; const float* Vsb3 = (const float*)d_in[26];

    const int ncell = in_sizes[0];          // 1,260,000
    const int ncl   = in_sizes[3];          // 420,000
    const int nv    = NV_CONST;
    const int nl    = 2 * nv;
    const int ng    = NG_CONST;

    size_t off = 0;
    auto A = [&](size_t bytes) -> void* {
        void* q = (char*)d_ws + off;
        off = (off + bytes + 255) & ~(size_t)255;
        return q;
    };
    short* Cb    = (short*)A((size_t)ncl * 80 * 2);    // raw C state (bf16)
    short* Lraw  = (short*)A((size_t)nl * 80 * 2);     // raw L state (bf16)
    short* Lb    = (short*)A((size_t)nv * 160 * 2);    // pre-normed L [v|v+nv]
    short* CLb   = (short*)A((size_t)nl * 80 * 2);     // normalized CL messages
    float* logits = (float*)A((size_t)nv * 4);
    float* slabC  = (float*)A(33 * 160 * 4);
    float* slabL  = (float*)A(33 * 160 * 4);
    float* loss_a = (float*)A(256);
    int* litrow  = (int*)A((size_t)ncell * 4);
    int* row_ptr = (int*)A((size_t)(nl + 1) * 4);
    int* tmp     = (int*)A((size_t)nl * 4);
    int* cl_of   = (int*)A((size_t)ncell * 4);
    short* CuW0p = (short*)A((size_t)10 * 5 * 64 * 16);
    short* CuW1p = (short*)A((size_t)5  * 5 * 64 * 16);
    short* LuW0p = (short*)A((size_t)15 * 8 * 64 * 16);
    short* LuW1p = (short*)A((size_t)5  * 8 * 64 * 16);
    short* VsW0p = (short*)A((size_t)10 * 5 * 64 * 16);
    short* VsW1p = (short*)A((size_t)10 * 5 * 64 * 16);
    short* VsW2p = (short*)A((size_t)10 * 5 * 64 * 16);

    const dim3 B64x4(64, 4, 1);

    // ---- setup ----
    k_zero_i<<<(nl + 255) / 256, 256, 0, stream>>>(tmp, nl);
    k_init_slabs<<<(33 * 160 + 255) / 256, 256, 0, stream>>>(slabC, slabL, loss_a, (float)ncl);
    k_litrow<<<(ncell + 255) / 256, 256, 0, stream>>>(lit_var, lit_neg, litrow, tmp, ncell, nv);
    k_scan4<<<1, 1024, 0, stream>>>(tmp, row_ptr, nl, ncell);
    k_copy_int<<<(nl + 255) / 256, 256, 0, stream>>>(tmp, row_ptr, nl);
    k_fill_csr<<<(ncell + 255) / 256, 256, 0, stream>>>(litrow, clause_idx, tmp, cl_of, ncell);
    k_fill_b<<<(ncl * 80 + 255) / 256, 256, 0, stream>>>(Cb, ncl * 80, Cscale);
    k_fill_b<<<(nl * 80 + 255) / 256, 256, 0, stream>>>(Lraw, nl * 80, Lscale);
    k_fill_b<<<(nv * 160 + 255) / 256, 256, 0, stream>>>(Lb, nv * 160, Lscale);
    k_pack_w<<<(10 * 5 * 64 + 255) / 256, 256, 0, stream>>>(CuW0, CuW0p, 160, 160, 5, 10);
    k_pack_w<<<(5  * 5 * 64 + 255) / 256, 256, 0, stream>>>(CuW1, CuW1p, 160, 80, 5, 5);
    k_pack_w<<<(15 * 8 * 64 + 255) / 256, 256, 0, stream>>>(LuW0, LuW0p, 240, 240, 8, 15);
    k_pack_w<<<(5  * 8 * 64 + 255) / 256, 256, 0, stream>>>(LuW1, LuW1p, 240, 80, 8, 5);
    k_pack_w<<<(10 * 5 * 64 + 255) / 256, 256, 0, stream>>>(VsW0, VsW0p, 160, 160, 5, 10);
    k_pack_w<<<(10 * 5 * 64 + 255) / 256, 256, 0, stream>>>(VsW1, VsW1p, 160, 160, 5, 10);
    k_pack_w<<<(10 * 5 * 64 + 255) / 256, 256, 0, stream>>>(VsW2, VsW2p, 160, 160, 5, 10);

    const int cblk = (ncl + 63) / 64;       // 6563
    const int lblk = nv / 32;               // 3125
    const int vblk = (nv + 63) / 64;        // 1563
    const int gblk = (nl * 20 + 255) / 256; // 15625
    const float MinvC = 1.f / (float)ncl;
    const float MinvL = 1.f / (float)nl;

    for (int r = 0; r < NROUNDS; ++r) {
        float* sCr  = slabC + (size_t)r * 160;        // stats of input C state
        float* sCr1 = slabC + (size_t)(r + 1) * 160;  // stats of new C (this round)
        float* sLr1 = slabL + (size_t)(r + 1) * 160;  // stats of new L (this round)
        k_c_update<<<cblk, B64x4, 0, stream>>>(
            Cb, Lb, litrow, LCs, (const short8*)CuW0p, Cub0, (const short8*)CuW1p, Cub1,
            sCr, sCr1, MinvC, ncl, nv);
        k_cl_gather<<<gblk, 256, 0, stream>>>(Cb, row_ptr, cl_of, CLs, sCr1, MinvC, CLb, nl);
        k_l_update<<<lblk, B64x4, 0, stream>>>(
            Lraw, Lb, CLb, (const short8*)LuW0p, Lub0, (const short8*)LuW1p, Lub1, sLr1, nv);
        k_v_head<<<vblk, B64x4, 0, stream>>>(
            Lraw, sLr1, MinvL, (const short8*)VsW0p, Vsb0, (const short8*)VsW1p, Vsb1,
            (const short8*)VsW2p, Vsb2, VsW3, Vsb3, logits, Lb, nv);
        k_loss<<<ng, 256, 0, stream>>>(logits, lit_var, lit_neg, loss_a, ncl / ng);
    }

    k_output<<<(nv + 1 + 255) / 256, 256, 0, stream>>>((float*)d_out, logits, loss_a, nv);
}